// Round 1
// baseline (7099.989 us; speedup 1.0000x reference)
//
#include <hip/hip_runtime.h>
#include <math.h>

#define B_   2
#define T_   1024
#define D_   1024
#define H_   16
#define DH_  64
#define DFF_ 4096
#define V_   32000
#define NTOK 2046      // B*(T-1)
#define NCH  250       // V_/128 vocab chunks for loss partials

// ---------------- small helpers ----------------
__device__ __forceinline__ float gelu_tanh(float x) {
    float x3 = x * x * x;
    return 0.5f * x * (1.0f + tanhf(0.7978845608028654f * (x + 0.044715f * x3)));
}

// ---------------- LoRA merge: out = W + 2.0 * A@Bm  (A [1024,8], Bm [8,N]) ----------------
__global__ void k_lora_merge(const float* __restrict__ W, const float* __restrict__ A,
                             const float* __restrict__ Bm, float* __restrict__ out, int N) {
    int idx = blockIdx.x * 256 + threadIdx.x;
    if (idx >= 1024 * N) return;
    int d = idx / N, n = idx % N;
    float s = 0.f;
#pragma unroll
    for (int r = 0; r < 8; r++) s += A[d * 8 + r] * Bm[r * N + n];
    out[idx] = W[idx] + 2.0f * s;
}

// ---------------- embedding gather ----------------
__global__ void k_embed_gather(const int* __restrict__ ids, const float* __restrict__ embed,
                               float* __restrict__ embeds) {
    int bt = blockIdx.x;         // 0..B*T-1
    int d4 = threadIdx.x;        // 0..255 (float4 index)
    int id = ids[bt];
    ((float4*)embeds)[(size_t)bt * 256 + d4] = ((const float4*)embed)[(size_t)id * 256 + d4];
}

// ---------------- h = embeds + Wpos for positions [c0, c0+range) ----------------
__global__ void k_hinit(const float* __restrict__ embeds, const float* __restrict__ Wpos,
                        float* __restrict__ hbuf, int c0, int range) {
    int r = blockIdx.x;          // 0..B*range-1
    int d4 = threadIdx.x;
    int b = r / range, pos = c0 + r % range;
    float4 e = ((const float4*)embeds)[(size_t)(b * T_ + pos) * 256 + d4];
    float4 w = ((const float4*)Wpos)[(size_t)pos * 256 + d4];
    float4 o;
    o.x = e.x + w.x; o.y = e.y + w.y; o.z = e.z + w.z; o.w = e.w + w.w;
    ((float4*)hbuf)[(size_t)(b * T_ + pos) * 256 + d4] = o;
}

// ---------------- LayerNorm over D=1024; in strided by (b,pos); out contiguous or strided ----------------
__global__ __launch_bounds__(256) void k_ln(const float* __restrict__ in, const float* __restrict__ sc,
                                            const float* __restrict__ bi, float* __restrict__ out,
                                            int c0, int range, int strided_out) {
    int r = blockIdx.x;
    int b = r / range, pos = c0 + r % range;
    const float* x = in + (size_t)(b * T_ + pos) * D_;
    int tid = threadIdx.x;
    float s1 = 0.f, s2 = 0.f;
#pragma unroll
    for (int i = tid; i < D_; i += 256) { float v = x[i]; s1 += v; s2 += v * v; }
    __shared__ float r1[256], r2[256];
    r1[tid] = s1; r2[tid] = s2; __syncthreads();
    for (int o = 128; o > 0; o >>= 1) {
        if (tid < o) { r1[tid] += r1[tid + o]; r2[tid] += r2[tid + o]; }
        __syncthreads();
    }
    float mean = r1[0] * (1.0f / D_);
    float var = r2[0] * (1.0f / D_) - mean * mean;
    float inv = rsqrtf(var + 1e-5f);
    float* o = strided_out ? out + (size_t)(b * T_ + pos) * D_ : out + (size_t)r * D_;
#pragma unroll
    for (int i = tid; i < D_; i += 256) o[i] = (x[i] - mean) * inv * sc[i] + bi[i];
}

// ---------------- generic tiled fp32 GEMM: C[M,N] = A[M,K] @ W[K,N]; epilogue by MODE ----------------
// MODE 1: qkv scatter (bias bqkv): n<1024 -> o0=qbuf[r*1024+n]; n<2048 -> o1=kcache[(b*T+pos)*1024+n-1024]; else o2=vcache
// MODE 2: residual accumulate: o0=hbuf[(b*T+pos)*D + n] += acc + bias[n]
// MODE 3: gelu write: o0[r*N+n] = gelu(acc + bias[n])
template <int MODE>
__global__ __launch_bounds__(256) void k_gemm(const float* __restrict__ A, const float* __restrict__ W,
                                              const float* __restrict__ bias,
                                              float* __restrict__ o0, float* __restrict__ o1,
                                              float* __restrict__ o2,
                                              int M, int N, int K, int c0, int range) {
    __shared__ float As[64][17];
    __shared__ float Ws[16][68];
    int row0 = blockIdx.y * 64, col0 = blockIdx.x * 64;
    int tid = threadIdx.x;
    int ty = tid / 16, tx = tid % 16;
    float acc[4][4] = {};
    for (int k0 = 0; k0 < K; k0 += 16) {
        {   // A tile: 64 rows x 16 k
            int ar = tid / 4, ak = (tid % 4) * 4;
            int grow = row0 + ar;
            float4 v = make_float4(0.f, 0.f, 0.f, 0.f);
            if (grow < M) v = *(const float4*)&A[(size_t)grow * K + k0 + ak];
            As[ar][ak + 0] = v.x; As[ar][ak + 1] = v.y; As[ar][ak + 2] = v.z; As[ar][ak + 3] = v.w;
        }
        {   // W tile: 16 k x 64 n
            int wk = tid / 16, wn = (tid % 16) * 4;
            float4 v = *(const float4*)&W[(size_t)(k0 + wk) * N + col0 + wn];
            Ws[wk][wn + 0] = v.x; Ws[wk][wn + 1] = v.y; Ws[wk][wn + 2] = v.z; Ws[wk][wn + 3] = v.w;
        }
        __syncthreads();
#pragma unroll
        for (int kk = 0; kk < 16; kk++) {
            float a[4];
#pragma unroll
            for (int i = 0; i < 4; i++) a[i] = As[ty * 4 + i][kk];
            float4 b4 = *(float4*)&Ws[kk][tx * 4];
            float bb[4] = {b4.x, b4.y, b4.z, b4.w};
#pragma unroll
            for (int i = 0; i < 4; i++)
#pragma unroll
                for (int j = 0; j < 4; j++) acc[i][j] += a[i] * bb[j];
        }
        __syncthreads();
    }
#pragma unroll
    for (int i = 0; i < 4; i++) {
        int r = row0 + ty * 4 + i;
        if (r >= M) continue;
        int b = r / range, pos = c0 + r % range;
#pragma unroll
        for (int j = 0; j < 4; j++) {
            int n = col0 + tx * 4 + j;
            float v = acc[i][j] + bias[n];
            if constexpr (MODE == 1) {
                if (n < 1024) o0[(size_t)r * 1024 + n] = v;
                else if (n < 2048) o1[(size_t)(b * T_ + pos) * 1024 + (n - 1024)] = v;
                else o2[(size_t)(b * T_ + pos) * 1024 + (n - 2048)] = v;
            } else if constexpr (MODE == 2) {
                o0[(size_t)(b * T_ + pos) * D_ + n] += v;
            } else if constexpr (MODE == 3) {
                o0[(size_t)r * N + n] = gelu_tanh(v);
            }
        }
    }
}

// ---------------- causal flash-row attention: one wave per (b, h, query) ----------------
__global__ __launch_bounds__(64) void k_attn(const float* __restrict__ qbuf, const float* __restrict__ kc,
                                             const float* __restrict__ vc, float* __restrict__ ctxbuf,
                                             int c0, int range) {
    int qi = blockIdx.x, h = blockIdx.y, b = blockIdx.z;
    int lane = threadIdx.x;
    int qpos = c0 + qi;
    int r = b * range + qi;
    float qv = qbuf[(size_t)r * D_ + h * 64 + lane] * 0.125f;   // /sqrt(64)
    const float* kbase = kc + (size_t)b * T_ * D_ + h * 64 + lane;
    const float* vbase = vc + (size_t)b * T_ * D_ + h * 64 + lane;
    float m = -1e30f, l = 0.f, acc = 0.f;
    for (int k = 0; k <= qpos; k++) {
        float p = qv * kbase[(size_t)k * D_];
#pragma unroll
        for (int o = 32; o > 0; o >>= 1) p += __shfl_xor(p, o, 64);
        float mn = fmaxf(m, p);
        float eo = __expf(m - mn), en = __expf(p - mn);
        l = l * eo + en;
        acc = acc * eo + en * vbase[(size_t)k * D_];
        m = mn;
    }
    ctxbuf[(size_t)r * D_ + h * 64 + lane] = acc / l;
}

// ---------------- latent vec fills ----------------
__global__ void k_latent0(const float* __restrict__ hid, const float* __restrict__ lw,
                          float* __restrict__ embeds) {
    int idx = blockIdx.x * 256 + threadIdx.x;     // B*D
    if (idx >= B_ * D_) return;
    int b = idx / D_, d = idx % D_;
    float w0 = lw[0], w1 = lw[1], w2 = lw[2];
    float mx = fmaxf(w0, fmaxf(w1, w2));
    float e0 = __expf(w0 - mx), e1 = __expf(w1 - mx), e2 = __expf(w2 - mx);
    float inv = 1.0f / (e0 + e1 + e2);
    float v = (e0 * hid[(size_t)(b * T_ + 509) * D_ + d] +
               e1 * hid[(size_t)(b * T_ + 510) * D_ + d] +
               e2 * hid[(size_t)(b * T_ + 511) * D_ + d]) * inv;
    embeds[(size_t)(b * T_ + 512) * D_ + d] = v;
}

__global__ void k_latent1(const float* __restrict__ hid, float* __restrict__ embeds, int tok) {
    int idx = blockIdx.x * 256 + threadIdx.x;     // B*D
    if (idx >= B_ * D_) return;
    int b = idx / D_, d = idx % D_;
    embeds[(size_t)(b * T_ + tok) * D_ + d] = hid[(size_t)(b * T_ + tok - 1) * D_ + d];
}

// ---------------- loss phase 1: fused logits GEMM (hid @ embed^T) + per-chunk row reduce ----------------
// grid (NCH, ceil(NTOK/64)); tile 64 tokens x 128 vocab, K=1024
__global__ __launch_bounds__(256) void k_loss1(const float* __restrict__ hid, const float* __restrict__ embed,
                                               const int* __restrict__ labels,
                                               float* __restrict__ partm, float* __restrict__ parts,
                                               float* __restrict__ llogit) {
    __shared__ float As[16][68];     // [kk][token row]
    __shared__ float Es[16][132];    // [kk][vocab col]
    __shared__ float Cs[64][129];
    int chunk = blockIdx.x, tile = blockIdx.y;
    int tid = threadIdx.x;
    int tok0 = tile * 64, v0 = chunk * 128;
    int ty = tid / 32, tx = tid % 32;
    float acc[8][4] = {};
    for (int k0 = 0; k0 < 1024; k0 += 16) {
        {   // A: 64 tokens x 16 k -> transposed to As[kk][row]
            int row = tid / 4, kq = (tid % 4) * 4;
            int tok = tok0 + row;
            float4 v = make_float4(0.f, 0.f, 0.f, 0.f);
            if (tok < NTOK) {
                int b = tok / 1023, t = tok % 1023;
                v = *(const float4*)&hid[(size_t)(b * T_ + t) * D_ + k0 + kq];
            }
            As[kq + 0][row] = v.x; As[kq + 1][row] = v.y; As[kq + 2][row] = v.z; As[kq + 3][row] = v.w;
        }
        {   // E: 128 vocab rows x 16 k -> Es[kk][col]
            int vr = tid / 2, kq = (tid % 2) * 8;
            const float* src = &embed[(size_t)(v0 + vr) * D_ + k0 + kq];
            float4 a = *(const float4*)src;
            float4 b4 = *(const float4*)(src + 4);
            Es[kq + 0][vr] = a.x;  Es[kq + 1][vr] = a.y;  Es[kq + 2][vr] = a.z;  Es[kq + 3][vr] = a.w;
            Es[kq + 4][vr] = b4.x; Es[kq + 5][vr] = b4.y; Es[kq + 6][vr] = b4.z; Es[kq + 7][vr] = b4.w;
        }
        __syncthreads();
#pragma unroll
        for (int kk = 0; kk < 16; kk++) {
            float4 a0 = *(float4*)&As[kk][ty * 8];
            float4 a1 = *(float4*)&As[kk][ty * 8 + 4];
            float4 e0 = *(float4*)&Es[kk][tx * 4];
            float a[8] = {a0.x, a0.y, a0.z, a0.w, a1.x, a1.y, a1.z, a1.w};
            float e[4] = {e0.x, e0.y, e0.z, e0.w};
#pragma unroll
            for (int i = 0; i < 8; i++)
#pragma unroll
                for (int j = 0; j < 4; j++) acc[i][j] += a[i] * e[j];
        }
        __syncthreads();
    }
#pragma unroll
    for (int i = 0; i < 8; i++)
#pragma unroll
        for (int j = 0; j < 4; j++) Cs[ty * 8 + i][tx * 4 + j] = acc[i][j];
    __syncthreads();
    if (tid < 64) {
        int tok = tok0 + tid;
        if (tok < NTOK) {
            float mx = -1e30f;
            for (int j = 0; j < 128; j++) mx = fmaxf(mx, Cs[tid][j]);
            float s = 0.f;
            for (int j = 0; j < 128; j++) s += __expf(Cs[tid][j] - mx);
            partm[(size_t)chunk * NTOK + tok] = mx;
            parts[(size_t)chunk * NTOK + tok] = s;
            int b = tok / 1023, t = tok % 1023;
            int lab = labels[b * T_ + t + 1];
            if (lab >= v0 && lab < v0 + 128) llogit[tok] = Cs[tid][lab - v0];
        }
    }
}

// ---------------- loss phase 2a: combine chunk partials -> per-token nll ----------------
__global__ void k_loss2a(const float* __restrict__ partm, const float* __restrict__ parts,
                         const float* __restrict__ ll, float* __restrict__ nll) {
    int tok = blockIdx.x * 256 + threadIdx.x;
    if (tok >= NTOK) return;
    float m0 = -1e30f, m1 = -1e30f, m2 = -1e30f, m3 = -1e30f;
    for (int c = 0; c < 248; c += 4) {
        m0 = fmaxf(m0, partm[(size_t)(c + 0) * NTOK + tok]);
        m1 = fmaxf(m1, partm[(size_t)(c + 1) * NTOK + tok]);
        m2 = fmaxf(m2, partm[(size_t)(c + 2) * NTOK + tok]);
        m3 = fmaxf(m3, partm[(size_t)(c + 3) * NTOK + tok]);
    }
    m0 = fmaxf(m0, partm[(size_t)248 * NTOK + tok]);
    m1 = fmaxf(m1, partm[(size_t)249 * NTOK + tok]);
    float M = fmaxf(fmaxf(m0, m1), fmaxf(m2, m3));
    float s0 = 0.f, s1 = 0.f, s2 = 0.f, s3 = 0.f;
    for (int c = 0; c < 248; c += 4) {
        s0 += parts[(size_t)(c + 0) * NTOK + tok] * __expf(partm[(size_t)(c + 0) * NTOK + tok] - M);
        s1 += parts[(size_t)(c + 1) * NTOK + tok] * __expf(partm[(size_t)(c + 1) * NTOK + tok] - M);
        s2 += parts[(size_t)(c + 2) * NTOK + tok] * __expf(partm[(size_t)(c + 2) * NTOK + tok] - M);
        s3 += parts[(size_t)(c + 3) * NTOK + tok] * __expf(partm[(size_t)(c + 3) * NTOK + tok] - M);
    }
    s0 += parts[(size_t)248 * NTOK + tok] * __expf(partm[(size_t)248 * NTOK + tok] - M);
    s1 += parts[(size_t)249 * NTOK + tok] * __expf(partm[(size_t)249 * NTOK + tok] - M);
    float S = s0 + s1 + s2 + s3;
    nll[tok] = logf(S) + M - ll[tok];
}

// ---------------- loss phase 2b: mean ----------------
__global__ __launch_bounds__(256) void k_loss2b(const float* __restrict__ nll, float* __restrict__ out) {
    __shared__ float red[256];
    int tid = threadIdx.x;
    float s = 0.f;
    for (int i = tid; i < NTOK; i += 256) s += nll[i];
    red[tid] = s; __syncthreads();
    for (int o = 128; o > 0; o >>= 1) {
        if (tid < o) red[tid] += red[tid + o];
        __syncthreads();
    }
    if (tid == 0) out[0] = red[0] / (float)NTOK;
}

// ---------------- host ----------------
extern "C" void kernel_launch(void* const* d_in, const int* in_sizes, int n_in,
                              void* d_out, int out_size, void* d_ws, size_t ws_size,
                              hipStream_t stream) {
    const int*   input_ids = (const int*)d_in[0];
    const int*   labels    = (const int*)d_in[2];
    const float* embed     = (const float*)d_in[4];
    const float* Wpos      = (const float*)d_in[5];
    const float* Wqkv      = (const float*)d_in[6];
    const float* bqkv      = (const float*)d_in[7];
    const float* Aq        = (const float*)d_in[8];
    const float* Bq        = (const float*)d_in[9];
    const float* Wo        = (const float*)d_in[10];
    const float* bo        = (const float*)d_in[11];
    const float* Ao        = (const float*)d_in[12];
    const float* Bo        = (const float*)d_in[13];
    const float* W1        = (const float*)d_in[14];
    const float* b1        = (const float*)d_in[15];
    const float* W2        = (const float*)d_in[16];
    const float* b2        = (const float*)d_in[17];
    const float* ln1_s     = (const float*)d_in[18];
    const float* ln1_b     = (const float*)d_in[19];
    const float* ln2_s     = (const float*)d_in[20];
    const float* ln2_b     = (const float*)d_in[21];
    const float* lnf_s     = (const float*)d_in[22];
    const float* lnf_b     = (const float*)d_in[23];
    const float* latent_w  = (const float*)d_in[24];

    float* ws = (float*)d_ws;
    // workspace layout (floats); total ~23.05M floats = ~92.2 MB
    float* wqkv_eff = ws;                    // 3,145,728
    float* wo_eff   = ws + 3145728;          // 1,048,576
    float* embeds   = ws + 4194304;          // 2,097,152
    float* hbuf     = ws + 6291456;          // 2,097,152
    float* hidbuf   = ws + 8388608;          // 2,097,152
    float* kcache   = ws + 10485760;         // 2,097,152
    float* vcache   = ws + 12582912;         // 2,097,152
    float* abuf     = ws + 14680064;         // 1,048,576 (range-local LN out)
    float* qbuf     = ws + 15728640;         // 1,048,576
    float* ctxbuf   = ws + 16777216;         // 1,048,576
    float* ffbuf    = ws + 17825792;         // 4,194,304
    float* partm    = ws + 22020096;         // 511,500
    float* parts_   = ws + 22531596;         // 511,500
    float* llogit   = ws + 23043096;         // 2,046
    float* nllbuf   = ws + 23045142;         // 2,046

    // LoRA-merged weights
    k_lora_merge<<<(1024 * 3072 + 255) / 256, 256, 0, stream>>>(Wqkv, Aq, Bq, wqkv_eff, 3072);
    k_lora_merge<<<(1024 * 1024 + 255) / 256, 256, 0, stream>>>(Wo, Ao, Bo, wo_eff, 1024);
    k_embed_gather<<<B_ * T_, 256, 0, stream>>>(input_ids, embed, embeds);

    auto run_pass = [&](int c0, int c1) {
        int range = c1 - c0;
        int Mr = B_ * range;
        int gy = (Mr + 63) / 64;
        k_hinit<<<Mr, 256, 0, stream>>>(embeds, Wpos, hbuf, c0, range);
        k_ln<<<Mr, 256, 0, stream>>>(hbuf, ln1_s, ln1_b, abuf, c0, range, 0);
        k_gemm<1><<<dim3(3072 / 64, gy), 256, 0, stream>>>(abuf, wqkv_eff, bqkv, qbuf, kcache, vcache,
                                                           Mr, 3072, 1024, c0, range);
        k_attn<<<dim3(range, H_, B_), 64, 0, stream>>>(qbuf, kcache, vcache, ctxbuf, c0, range);
        k_gemm<2><<<dim3(1024 / 64, gy), 256, 0, stream>>>(ctxbuf, wo_eff, bo, hbuf, nullptr, nullptr,
                                                           Mr, 1024, 1024, c0, range);
        k_ln<<<Mr, 256, 0, stream>>>(hbuf, ln2_s, ln2_b, abuf, c0, range, 0);
        k_gemm<3><<<dim3(4096 / 64, gy), 256, 0, stream>>>(abuf, W1, b1, ffbuf, nullptr, nullptr,
                                                           Mr, 4096, 1024, c0, range);
        k_gemm<2><<<dim3(1024 / 64, gy), 256, 0, stream>>>(ffbuf, W2, b2, hbuf, nullptr, nullptr,
                                                           Mr, 1024, 4096, c0, range);
        k_ln<<<Mr, 256, 0, stream>>>(hbuf, lnf_s, lnf_b, hidbuf, c0, range, 1);
    };

    run_pass(0, 512);
    k_latent0<<<(B_ * D_ + 255) / 256, 256, 0, stream>>>(hidbuf, latent_w, embeds);
    run_pass(512, 513);
    k_latent1<<<(B_ * D_ + 255) / 256, 256, 0, stream>>>(hidbuf, embeds, 513);
    run_pass(513, 514);
    k_latent1<<<(B_ * D_ + 255) / 256, 256, 0, stream>>>(hidbuf, embeds, 514);
    run_pass(514, 515);
    k_latent1<<<(B_ * D_ + 255) / 256, 256, 0, stream>>>(hidbuf, embeds, 515);
    run_pass(515, 1024);

    // loss
    k_loss1<<<dim3(NCH, (NTOK + 63) / 64), 256, 0, stream>>>(hidbuf, embed, labels, partm, parts_, llogit);
    k_loss2a<<<(NTOK + 255) / 256, 256, 0, stream>>>(partm, parts_, llogit, nllbuf);
    k_loss2b<<<1, 256, 0, stream>>>(nllbuf, (float*)d_out);
}

// Round 2
// 3865.505 us; speedup vs baseline: 1.8368x; 1.8368x over previous
//
#include <hip/hip_runtime.h>
#include <math.h>

#define B_   2
#define T_   1024
#define D_   1024
#define H_   16
#define DH_  64
#define DFF_ 4096
#define V_   32000
#define NTOK 2046      // B*(T-1)
#define NCH  250       // V_/128 vocab chunks for loss partials

typedef __attribute__((ext_vector_type(8))) short short8;
typedef __attribute__((ext_vector_type(4))) float floatx4;

__device__ __forceinline__ unsigned short f2bf(float x) {
    unsigned int u = __float_as_uint(x);
    unsigned int r = (u + 0x7fffu + ((u >> 16) & 1u)) >> 16;
    return (unsigned short)r;
}

__device__ __forceinline__ void gld_lds16(void* lds, const void* g) {
    __builtin_amdgcn_global_load_lds(
        (const __attribute__((address_space(1))) void*)g,
        (__attribute__((address_space(3))) void*)lds, 16, 0, 0);
}

__device__ __forceinline__ float gelu_tanh(float x) {
    float x3 = x * x * x;
    return 0.5f * x * (1.0f + tanhf(0.7978845608028654f * (x + 0.044715f * x3)));
}

// ---------------- weight prep: out[n*K+k] = bf16(W[k*N+n] + 2*(A@Bm)[k,n]) ----------------
__global__ __launch_bounds__(256) void k_prep_w(const float* __restrict__ W,
        const float* __restrict__ A, const float* __restrict__ Bm,
        unsigned short* __restrict__ out, int K, int N, int lora) {
    __shared__ float t[64][65];
    int n0 = blockIdx.x * 64, k0 = blockIdx.y * 64;
    int tid = threadIdx.x;
    int nn = tid & 63, kb = tid >> 6;
    for (int i = 0; i < 16; i++) {
        int kk = kb * 16 + i;
        float v = W[(size_t)(k0 + kk) * N + n0 + nn];
        if (lora) {
            float s = 0.f;
#pragma unroll
            for (int r = 0; r < 8; r++) s += A[(k0 + kk) * 8 + r] * Bm[r * N + n0 + nn];
            v += 2.0f * s;
        }
        t[kk][nn] = v;
    }
    __syncthreads();
    int kk2 = tid & 63, nb = tid >> 6;
    for (int j = 0; j < 16; j++) {
        int nn2 = nb * 16 + j;
        out[(size_t)(n0 + nn2) * K + k0 + kk2] = f2bf(t[kk2][nn2]);
    }
}

// ---------------- fp32 -> bf16 bulk convert (n4 = n/4 float4 groups) ----------------
__global__ void k_f2bf(const float* __restrict__ in, unsigned short* __restrict__ out, int n4) {
    int i = blockIdx.x * 256 + threadIdx.x;
    if (i >= n4) return;
    float4 v = ((const float4*)in)[i];
    ushort4 o;
    o.x = f2bf(v.x); o.y = f2bf(v.y); o.z = f2bf(v.z); o.w = f2bf(v.w);
    ((ushort4*)out)[i] = o;
}

// ---------------- embedding gather ----------------
__global__ void k_embed_gather(const int* __restrict__ ids, const float* __restrict__ embed,
                               float* __restrict__ embeds) {
    int bt = blockIdx.x;
    int d4 = threadIdx.x;
    int id = ids[bt];
    ((float4*)embeds)[(size_t)bt * 256 + d4] = ((const float4*)embed)[(size_t)id * 256 + d4];
}

// ---------------- h = embeds + Wpos ----------------
__global__ void k_hinit(const float* __restrict__ embeds, const float* __restrict__ Wpos,
                        float* __restrict__ hbuf, int c0, int range) {
    int r = blockIdx.x;
    int d4 = threadIdx.x;
    int b = r / range, pos = c0 + r % range;
    float4 e = ((const float4*)embeds)[(size_t)(b * T_ + pos) * 256 + d4];
    float4 w = ((const float4*)Wpos)[(size_t)pos * 256 + d4];
    float4 o;
    o.x = e.x + w.x; o.y = e.y + w.y; o.z = e.z + w.z; o.w = e.w + w.w;
    ((float4*)hbuf)[(size_t)(b * T_ + pos) * 256 + d4] = o;
}

// ---------------- LayerNorm; optional fp32 strided out + bf16 out (strided or compact) ----------------
__global__ __launch_bounds__(256) void k_ln(const float* __restrict__ in, const float* __restrict__ sc,
                                            const float* __restrict__ bi, float* __restrict__ outf,
                                            unsigned short* __restrict__ outbf,
                                            int c0, int range, int strided_bf) {
    int r = blockIdx.x;
    int b = r / range, pos = c0 + r % range;
    const float* x = in + (size_t)(b * T_ + pos) * D_;
    int tid = threadIdx.x;
    float s1 = 0.f, s2 = 0.f;
#pragma unroll
    for (int i = tid; i < D_; i += 256) { float v = x[i]; s1 += v; s2 += v * v; }
    __shared__ float r1[256], r2[256];
    r1[tid] = s1; r2[tid] = s2; __syncthreads();
    for (int o = 128; o > 0; o >>= 1) {
        if (tid < o) { r1[tid] += r1[tid + o]; r2[tid] += r2[tid + o]; }
        __syncthreads();
    }
    float mean = r1[0] * (1.0f / D_);
    float var = r2[0] * (1.0f / D_) - mean * mean;
    float inv = rsqrtf(var + 1e-5f);
    size_t bfrow = strided_bf ? (size_t)(b * T_ + pos) : (size_t)r;
#pragma unroll
    for (int i = tid; i < D_; i += 256) {
        float y = (x[i] - mean) * inv * sc[i] + bi[i];
        if (outf) outf[(size_t)(b * T_ + pos) * D_ + i] = y;
        outbf[bfrow * D_ + i] = f2bf(y);
    }
}

// ---------------- MFMA GEMM: C[M,N] = A[M,K](bf16) @ Bt[N,K]^T(bf16) ----------------
// MODE 1: qkv scatter fp32; MODE 2: residual add fp32; MODE 3: gelu -> bf16
template <int MODE>
__global__ __launch_bounds__(256) void k_mgemm(const unsigned short* __restrict__ Abf,
        const unsigned short* __restrict__ Bt, const float* __restrict__ bias,
        float* __restrict__ o0, float* __restrict__ o1, float* __restrict__ o2,
        unsigned short* __restrict__ obf,
        int M, int N, int K, int c0, int range) {
    __shared__ short8 As_v[512];
    __shared__ short8 Bs_v[512];
    int tid = threadIdx.x;
    int lane = tid & 63, w = tid >> 6;
    int quad = lane >> 4, l15 = lane & 15;
    int row0 = blockIdx.y * 128, col0 = blockIdx.x * 128;
    int rh = (w >> 1) * 64, ch = (w & 1) * 64;

    int cA0 = w * 128 + lane, cA1 = cA0 + 64;
    int rA0 = cA0 & 127, kgA0 = cA0 >> 7;
    int rA1 = cA1 & 127, kgA1 = cA1 >> 7;
    int rowA0 = row0 + rA0; if (rowA0 >= M) rowA0 = M - 1;
    int rowA1 = row0 + rA1; if (rowA1 >= M) rowA1 = M - 1;
    const unsigned short* ga0 = Abf + (size_t)rowA0 * K + kgA0 * 8;
    const unsigned short* ga1 = Abf + (size_t)rowA1 * K + kgA1 * 8;
    const unsigned short* gb0 = Bt + (size_t)(col0 + rA0) * K + kgA0 * 8;
    const unsigned short* gb1 = Bt + (size_t)(col0 + rA1) * K + kgA1 * 8;

    floatx4 acc[4][4];
#pragma unroll
    for (int i = 0; i < 4; i++)
#pragma unroll
        for (int j = 0; j < 4; j++)
#pragma unroll
            for (int k = 0; k < 4; k++) acc[i][j][k] = 0.f;

    int iters = K >> 5;
    for (int it = 0; it < iters; ++it) {
        __syncthreads();
        gld_lds16(&As_v[w * 128],      ga0);
        gld_lds16(&As_v[w * 128 + 64], ga1);
        gld_lds16(&Bs_v[w * 128],      gb0);
        gld_lds16(&Bs_v[w * 128 + 64], gb1);
        ga0 += 32; ga1 += 32; gb0 += 32; gb1 += 32;
        __syncthreads();
        short8 af[4], bfv[4];
#pragma unroll
        for (int mi = 0; mi < 4; mi++) af[mi] = As_v[quad * 128 + rh + mi * 16 + l15];
#pragma unroll
        for (int nj = 0; nj < 4; nj++) bfv[nj] = Bs_v[quad * 128 + ch + nj * 16 + l15];
#pragma unroll
        for (int mi = 0; mi < 4; mi++)
#pragma unroll
            for (int nj = 0; nj < 4; nj++)
                acc[mi][nj] = __builtin_amdgcn_mfma_f32_16x16x32_bf16(af[mi], bfv[nj], acc[mi][nj], 0, 0, 0);
    }

#pragma unroll
    for (int mi = 0; mi < 4; mi++)
#pragma unroll
        for (int reg = 0; reg < 4; reg++) {
            int r = row0 + rh + mi * 16 + quad * 4 + reg;
            if (r >= M) continue;
            int b = r / range, pos = c0 + r % range;
#pragma unroll
            for (int nj = 0; nj < 4; nj++) {
                int n = col0 + ch + nj * 16 + l15;
                float v = acc[mi][nj][reg] + bias[n];
                if constexpr (MODE == 1) {
                    if (n < 1024) o0[(size_t)r * 1024 + n] = v;
                    else if (n < 2048) o1[(size_t)(b * T_ + pos) * 1024 + (n - 1024)] = v;
                    else o2[(size_t)(b * T_ + pos) * 1024 + (n - 2048)] = v;
                } else if constexpr (MODE == 2) {
                    o0[(size_t)(b * T_ + pos) * D_ + n] += v;
                } else if constexpr (MODE == 3) {
                    obf[(size_t)r * N + n] = f2bf(gelu_tanh(v));
                }
            }
        }
}

// ---------------- loss MFMA GEMM: logits chunk + fused (max,sumexp,label) ----------------
__global__ __launch_bounds__(256) void k_loss1m(const unsigned short* __restrict__ hidbf,
        const unsigned short* __restrict__ embedbf, const int* __restrict__ labels,
        float* __restrict__ partm, float* __restrict__ parts, float* __restrict__ llogit) {
    __shared__ short8 As_v[512];
    __shared__ short8 Bs_v[512];
    __shared__ int lds_lab[128];
    __shared__ float lds_pm[128][2];
    __shared__ float lds_ps[128][2];
    int tid = threadIdx.x;
    int lane = tid & 63, w = tid >> 6;
    int quad = lane >> 4, l15 = lane & 15;
    int chunk = blockIdx.x;
    int row0 = blockIdx.y * 128, v0 = chunk * 128;
    int rh = (w >> 1) * 64, ch = (w & 1) * 64;

    if (tid < 128) {
        int tok = row0 + tid;
        lds_lab[tid] = (tok < NTOK) ? labels[tok + 1 + (tok >= 1023)] : -1;
    }

    int cA0 = w * 128 + lane, cA1 = cA0 + 64;
    int rA0 = cA0 & 127, kgA0 = cA0 >> 7;
    int rA1 = cA1 & 127, kgA1 = cA1 >> 7;
    int tokA0 = row0 + rA0; if (tokA0 >= NTOK) tokA0 = NTOK - 1;
    int tokA1 = row0 + rA1; if (tokA1 >= NTOK) tokA1 = NTOK - 1;
    const unsigned short* ga0 = hidbf + (size_t)(tokA0 + (tokA0 >= 1023)) * D_ + kgA0 * 8;
    const unsigned short* ga1 = hidbf + (size_t)(tokA1 + (tokA1 >= 1023)) * D_ + kgA1 * 8;
    const unsigned short* gb0 = embedbf + (size_t)(v0 + rA0) * D_ + kgA0 * 8;
    const unsigned short* gb1 = embedbf + (size_t)(v0 + rA1) * D_ + kgA1 * 8;

    floatx4 acc[4][4];
#pragma unroll
    for (int i = 0; i < 4; i++)
#pragma unroll
        for (int j = 0; j < 4; j++)
#pragma unroll
            for (int k = 0; k < 4; k++) acc[i][j][k] = 0.f;

    for (int it = 0; it < D_ / 32; ++it) {
        __syncthreads();
        gld_lds16(&As_v[w * 128],      ga0);
        gld_lds16(&As_v[w * 128 + 64], ga1);
        gld_lds16(&Bs_v[w * 128],      gb0);
        gld_lds16(&Bs_v[w * 128 + 64], gb1);
        ga0 += 32; ga1 += 32; gb0 += 32; gb1 += 32;
        __syncthreads();
        short8 af[4], bfv[4];
#pragma unroll
        for (int mi = 0; mi < 4; mi++) af[mi] = As_v[quad * 128 + rh + mi * 16 + l15];
#pragma unroll
        for (int nj = 0; nj < 4; nj++) bfv[nj] = Bs_v[quad * 128 + ch + nj * 16 + l15];
#pragma unroll
        for (int mi = 0; mi < 4; mi++)
#pragma unroll
            for (int nj = 0; nj < 4; nj++)
                acc[mi][nj] = __builtin_amdgcn_mfma_f32_16x16x32_bf16(af[mi], bfv[nj], acc[mi][nj], 0, 0, 0);
    }

#pragma unroll
    for (int mi = 0; mi < 4; mi++)
#pragma unroll
        for (int reg = 0; reg < 4; reg++) {
            int rloc = rh + mi * 16 + quad * 4 + reg;
            int lab = lds_lab[rloc];
            float vm = -1e30f;
#pragma unroll
            for (int nj = 0; nj < 4; nj++) {
                float v = acc[mi][nj][reg];
                int vcol = v0 + ch + nj * 16 + l15;
                if (vcol == lab) llogit[row0 + rloc] = v;
                vm = fmaxf(vm, v);
            }
            for (int off = 1; off < 16; off <<= 1) vm = fmaxf(vm, __shfl_xor(vm, off));
            float ss = 0.f;
#pragma unroll
            for (int nj = 0; nj < 4; nj++) ss += __expf(acc[mi][nj][reg] - vm);
            for (int off = 1; off < 16; off <<= 1) ss += __shfl_xor(ss, off);
            if (l15 == 0) { lds_pm[rloc][ch >> 6] = vm; lds_ps[rloc][ch >> 6] = ss; }
        }
    __syncthreads();
    if (tid < 128) {
        int tok = row0 + tid;
        if (tok < NTOK) {
            float m0 = lds_pm[tid][0], m1 = lds_pm[tid][1];
            float M = fmaxf(m0, m1);
            float S = lds_ps[tid][0] * __expf(m0 - M) + lds_ps[tid][1] * __expf(m1 - M);
            partm[(size_t)chunk * NTOK + tok] = M;
            parts[(size_t)chunk * NTOK + tok] = S;
        }
    }
}

// ---------------- causal flash-row attention (fp32 in, bf16 ctx out) ----------------
__global__ __launch_bounds__(64) void k_attn(const float* __restrict__ qbuf, const float* __restrict__ kc,
                                             const float* __restrict__ vc, unsigned short* __restrict__ ctxbf,
                                             int c0, int range) {
    int qi = blockIdx.x, h = blockIdx.y, b = blockIdx.z;
    int lane = threadIdx.x;
    int qpos = c0 + qi;
    int r = b * range + qi;
    float qv = qbuf[(size_t)r * D_ + h * 64 + lane] * 0.125f;
    const float* kbase = kc + (size_t)b * T_ * D_ + h * 64 + lane;
    const float* vbase = vc + (size_t)b * T_ * D_ + h * 64 + lane;
    float m = -1e30f, l = 0.f, acc = 0.f;
    for (int k = 0; k <= qpos; k++) {
        float p = qv * kbase[(size_t)k * D_];
#pragma unroll
        for (int o = 32; o > 0; o >>= 1) p += __shfl_xor(p, o, 64);
        float mn = fmaxf(m, p);
        float eo = __expf(m - mn), en = __expf(p - mn);
        l = l * eo + en;
        acc = acc * eo + en * vbase[(size_t)k * D_];
        m = mn;
    }
    ctxbf[(size_t)r * D_ + h * 64 + lane] = f2bf(acc / l);
}

// ---------------- latent vec fills ----------------
__global__ void k_latent0(const float* __restrict__ hid, const float* __restrict__ lw,
                          float* __restrict__ embeds) {
    int idx = blockIdx.x * 256 + threadIdx.x;
    if (idx >= B_ * D_) return;
    int b = idx / D_, d = idx % D_;
    float w0 = lw[0], w1 = lw[1], w2 = lw[2];
    float mx = fmaxf(w0, fmaxf(w1, w2));
    float e0 = __expf(w0 - mx), e1 = __expf(w1 - mx), e2 = __expf(w2 - mx);
    float inv = 1.0f / (e0 + e1 + e2);
    float v = (e0 * hid[(size_t)(b * T_ + 509) * D_ + d] +
               e1 * hid[(size_t)(b * T_ + 510) * D_ + d] +
               e2 * hid[(size_t)(b * T_ + 511) * D_ + d]) * inv;
    embeds[(size_t)(b * T_ + 512) * D_ + d] = v;
}

__global__ void k_latent1(const float* __restrict__ hid, float* __restrict__ embeds, int tok) {
    int idx = blockIdx.x * 256 + threadIdx.x;
    if (idx >= B_ * D_) return;
    int b = idx / D_, d = idx % D_;
    embeds[(size_t)(b * T_ + tok) * D_ + d] = hid[(size_t)(b * T_ + tok - 1) * D_ + d];
}

// ---------------- loss combine ----------------
__global__ void k_loss2a(const float* __restrict__ partm, const float* __restrict__ parts,
                         const float* __restrict__ ll, float* __restrict__ nll) {
    int tok = blockIdx.x * 256 + threadIdx.x;
    if (tok >= NTOK) return;
    float M = -1e30f;
    for (int c = 0; c < NCH; c++) M = fmaxf(M, partm[(size_t)c * NTOK + tok]);
    float S = 0.f;
    for (int c = 0; c < NCH; c++)
        S += parts[(size_t)c * NTOK + tok] * __expf(partm[(size_t)c * NTOK + tok] - M);
    nll[tok] = logf(S) + M - ll[tok];
}

__global__ __launch_bounds__(256) void k_loss2b(const float* __restrict__ nll, float* __restrict__ out) {
    __shared__ float red[256];
    int tid = threadIdx.x;
    float s = 0.f;
    for (int i = tid; i < NTOK; i += 256) s += nll[i];
    red[tid] = s; __syncthreads();
    for (int o = 128; o > 0; o >>= 1) {
        if (tid < o) red[tid] += red[tid + o];
        __syncthreads();
    }
    if (tid == 0) out[0] = red[0] / (float)NTOK;
}

// ---------------- host ----------------
extern "C" void kernel_launch(void* const* d_in, const int* in_sizes, int n_in,
                              void* d_out, int out_size, void* d_ws, size_t ws_size,
                              hipStream_t stream) {
    const int*   input_ids = (const int*)d_in[0];
    const int*   labels    = (const int*)d_in[2];
    const float* embed     = (const float*)d_in[4];
    const float* Wpos      = (const float*)d_in[5];
    const float* Wqkv      = (const float*)d_in[6];
    const float* bqkv      = (const float*)d_in[7];
    const float* Aq        = (const float*)d_in[8];
    const float* Bq        = (const float*)d_in[9];
    const float* Wo        = (const float*)d_in[10];
    const float* bo        = (const float*)d_in[11];
    const float* Ao        = (const float*)d_in[12];
    const float* Bo        = (const float*)d_in[13];
    const float* W1        = (const float*)d_in[14];
    const float* b1        = (const float*)d_in[15];
    const float* W2        = (const float*)d_in[16];
    const float* b2        = (const float*)d_in[17];
    const float* ln1_s     = (const float*)d_in[18];
    const float* ln1_b     = (const float*)d_in[19];
    const float* ln2_s     = (const float*)d_in[20];
    const float* ln2_b     = (const float*)d_in[21];
    const float* lnf_s     = (const float*)d_in[22];
    const float* lnf_b     = (const float*)d_in[23];
    const float* latent_w  = (const float*)d_in[24];

    char* base = (char*)d_ws;
    size_t off = 0;
    auto alloc = [&](size_t bytes) { void* p = base + off; off += (bytes + 255) & ~255ULL; return p; };

    float* embeds  = (float*)alloc((size_t)B_ * T_ * D_ * 4);
    float* hbuf    = (float*)alloc((size_t)B_ * T_ * D_ * 4);
    float* hidbuf  = (float*)alloc((size_t)B_ * T_ * D_ * 4);
    float* kcache  = (float*)alloc((size_t)B_ * T_ * D_ * 4);
    float* vcache  = (float*)alloc((size_t)B_ * T_ * D_ * 4);
    float* qbuf    = (float*)alloc((size_t)1024 * D_ * 4);
    float* partm   = (float*)alloc((size_t)NCH * NTOK * 4);
    float* parts_  = (float*)alloc((size_t)NCH * NTOK * 4);
    float* llogit  = (float*)alloc((size_t)NTOK * 4);
    float* nllbuf  = (float*)alloc((size_t)NTOK * 4);
    unsigned short* wqkvT  = (unsigned short*)alloc((size_t)3072 * 1024 * 2);
    unsigned short* woT    = (unsigned short*)alloc((size_t)1024 * 1024 * 2);
    unsigned short* W1T    = (unsigned short*)alloc((size_t)4096 * 1024 * 2);
    unsigned short* W2T    = (unsigned short*)alloc((size_t)1024 * 4096 * 2);
    unsigned short* embedbf = (unsigned short*)alloc((size_t)V_ * D_ * 2);
    unsigned short* hidbf  = (unsigned short*)alloc((size_t)B_ * T_ * D_ * 2);
    unsigned short* abf    = (unsigned short*)alloc((size_t)1024 * D_ * 2);
    unsigned short* ctxbf  = (unsigned short*)alloc((size_t)1024 * D_ * 2);
    unsigned short* ffbw   = (unsigned short*)alloc((size_t)1024 * DFF_ * 2);

    // weight prep (transpose + LoRA merge + bf16)
    k_prep_w<<<dim3(3072 / 64, 1024 / 64), 256, 0, stream>>>(Wqkv, Aq, Bq, wqkvT, 1024, 3072, 1);
    k_prep_w<<<dim3(1024 / 64, 1024 / 64), 256, 0, stream>>>(Wo, Ao, Bo, woT, 1024, 1024, 1);
    k_prep_w<<<dim3(4096 / 64, 1024 / 64), 256, 0, stream>>>(W1, nullptr, nullptr, W1T, 1024, 4096, 0);
    k_prep_w<<<dim3(1024 / 64, 4096 / 64), 256, 0, stream>>>(W2, nullptr, nullptr, W2T, 4096, 1024, 0);
    k_f2bf<<<(V_ * D_ / 4 + 255) / 256, 256, 0, stream>>>(embed, embedbf, V_ * D_ / 4);
    k_embed_gather<<<B_ * T_, 256, 0, stream>>>(input_ids, embed, embeds);

    auto run_pass = [&](int c0, int c1) {
        int range = c1 - c0;
        int Mr = B_ * range;
        int gy = (Mr + 127) / 128;
        k_hinit<<<Mr, 256, 0, stream>>>(embeds, Wpos, hbuf, c0, range);
        k_ln<<<Mr, 256, 0, stream>>>(hbuf, ln1_s, ln1_b, nullptr, abf, c0, range, 0);
        k_mgemm<1><<<dim3(3072 / 128, gy), 256, 0, stream>>>(abf, wqkvT, bqkv, qbuf, kcache, vcache,
                                                             nullptr, Mr, 3072, 1024, c0, range);
        k_attn<<<dim3(range, H_, B_), 64, 0, stream>>>(qbuf, kcache, vcache, ctxbf, c0, range);
        k_mgemm<2><<<dim3(1024 / 128, gy), 256, 0, stream>>>(ctxbf, woT, bo, hbuf, nullptr, nullptr,
                                                             nullptr, Mr, 1024, 1024, c0, range);
        k_ln<<<Mr, 256, 0, stream>>>(hbuf, ln2_s, ln2_b, nullptr, abf, c0, range, 0);
        k_mgemm<3><<<dim3(4096 / 128, gy), 256, 0, stream>>>(abf, W1T, b1, nullptr, nullptr, nullptr,
                                                             ffbw, Mr, 4096, 1024, c0, range);
        k_mgemm<2><<<dim3(1024 / 128, gy), 256, 0, stream>>>(ffbw, W2T, b2, hbuf, nullptr, nullptr,
                                                             nullptr, Mr, 1024, 4096, c0, range);
        k_ln<<<Mr, 256, 0, stream>>>(hbuf, lnf_s, lnf_b, hidbuf, hidbf, c0, range, 1);
    };

    run_pass(0, 512);
    k_latent0<<<(B_ * D_ + 255) / 256, 256, 0, stream>>>(hidbuf, latent_w, embeds);
    run_pass(512, 513);
    k_latent1<<<(B_ * D_ + 255) / 256, 256, 0, stream>>>(hidbuf, embeds, 513);
    run_pass(513, 514);
    k_latent1<<<(B_ * D_ + 255) / 256, 256, 0, stream>>>(hidbuf, embeds, 514);
    run_pass(514, 515);
    k_latent1<<<(B_ * D_ + 255) / 256, 256, 0, stream>>>(hidbuf, embeds, 515);
    run_pass(515, 1024);

    // loss
    k_loss1m<<<dim3(NCH, (NTOK + 127) / 128), 256, 0, stream>>>(hidbf, embedbf, labels, partm, parts_, llogit);
    k_loss2a<<<(NTOK + 255) / 256, 256, 0, stream>>>(partm, parts_, llogit, nllbuf);
    k_loss2b<<<1, 256, 0, stream>>>(nllbuf, (float*)d_out);
}

// Round 3
// 2059.524 us; speedup vs baseline: 3.4474x; 1.8769x over previous
//
#include <hip/hip_runtime.h>
#include <math.h>

#define B_   2
#define T_   1024
#define D_   1024
#define H_   16
#define DH_  64
#define DFF_ 4096
#define V_   32000
#define NTOK 2046      // B*(T-1)
#define NCH  250       // V_/128 vocab chunks for loss partials

typedef __attribute__((ext_vector_type(8))) short short8;
typedef __attribute__((ext_vector_type(4))) float floatx4;

__device__ __forceinline__ unsigned short f2bf(float x) {
    unsigned int u = __float_as_uint(x);
    unsigned int r = (u + 0x7fffu + ((u >> 16) & 1u)) >> 16;
    return (unsigned short)r;
}
__device__ __forceinline__ float bf2f(unsigned short u) {
    return __uint_as_float(((unsigned int)u) << 16);
}

__device__ __forceinline__ void gld_lds16(void* lds, const void* g) {
    __builtin_amdgcn_global_load_lds(
        (const __attribute__((address_space(1))) void*)g,
        (__attribute__((address_space(3))) void*)lds, 16, 0, 0);
}

__device__ __forceinline__ float gelu_tanh(float x) {
    float x3 = x * x * x;
    return 0.5f * x * (1.0f + tanhf(0.7978845608028654f * (x + 0.044715f * x3)));
}

// ---------------- weight prep: out[n*K+k] = bf16(W[k*N+n] + 2*(A@Bm)[k,n]) ----------------
__global__ __launch_bounds__(256) void k_prep_w(const float* __restrict__ W,
        const float* __restrict__ A, const float* __restrict__ Bm,
        unsigned short* __restrict__ out, int K, int N, int lora) {
    __shared__ float t[64][65];
    int n0 = blockIdx.x * 64, k0 = blockIdx.y * 64;
    int tid = threadIdx.x;
    int nn = tid & 63, kb = tid >> 6;
    for (int i = 0; i < 16; i++) {
        int kk = kb * 16 + i;
        float v = W[(size_t)(k0 + kk) * N + n0 + nn];
        if (lora) {
            float s = 0.f;
#pragma unroll
            for (int r = 0; r < 8; r++) s += A[(k0 + kk) * 8 + r] * Bm[r * N + n0 + nn];
            v += 2.0f * s;
        }
        t[kk][nn] = v;
    }
    __syncthreads();
    int kk2 = tid & 63, nb = tid >> 6;
    for (int j = 0; j < 16; j++) {
        int nn2 = nb * 16 + j;
        out[(size_t)(n0 + nn2) * K + k0 + kk2] = f2bf(t[kk2][nn2]);
    }
}

// ---------------- fp32 -> bf16 bulk convert ----------------
__global__ void k_f2bf(const float* __restrict__ in, unsigned short* __restrict__ out, int n4) {
    int i = blockIdx.x * 256 + threadIdx.x;
    if (i >= n4) return;
    float4 v = ((const float4*)in)[i];
    ushort4 o;
    o.x = f2bf(v.x); o.y = f2bf(v.y); o.z = f2bf(v.z); o.w = f2bf(v.w);
    ((ushort4*)out)[i] = o;
}

// ---------------- embedding gather ----------------
__global__ void k_embed_gather(const int* __restrict__ ids, const float* __restrict__ embed,
                               float* __restrict__ embeds) {
    int bt = blockIdx.x;
    int d4 = threadIdx.x;
    int id = ids[bt];
    ((float4*)embeds)[(size_t)bt * 256 + d4] = ((const float4*)embed)[(size_t)id * 256 + d4];
}

// ---------------- h = embeds + Wpos ----------------
__global__ void k_hinit(const float* __restrict__ embeds, const float* __restrict__ Wpos,
                        float* __restrict__ hbuf, int c0, int range) {
    int r = blockIdx.x;
    int d4 = threadIdx.x;
    int b = r / range, pos = c0 + r % range;
    float4 e = ((const float4*)embeds)[(size_t)(b * T_ + pos) * 256 + d4];
    float4 w = ((const float4*)Wpos)[(size_t)pos * 256 + d4];
    float4 o;
    o.x = e.x + w.x; o.y = e.y + w.y; o.z = e.z + w.z; o.w = e.w + w.w;
    ((float4*)hbuf)[(size_t)(b * T_ + pos) * 256 + d4] = o;
}

// ---------------- LayerNorm; optional fp32 strided out + bf16 out ----------------
__global__ __launch_bounds__(256) void k_ln(const float* __restrict__ in, const float* __restrict__ sc,
                                            const float* __restrict__ bi, float* __restrict__ outf,
                                            unsigned short* __restrict__ outbf,
                                            int c0, int range, int strided_bf) {
    int r = blockIdx.x;
    int b = r / range, pos = c0 + r % range;
    const float* x = in + (size_t)(b * T_ + pos) * D_;
    int tid = threadIdx.x;
    float s1 = 0.f, s2 = 0.f;
#pragma unroll
    for (int i = tid; i < D_; i += 256) { float v = x[i]; s1 += v; s2 += v * v; }
    __shared__ float r1[256], r2[256];
    r1[tid] = s1; r2[tid] = s2; __syncthreads();
    for (int o = 128; o > 0; o >>= 1) {
        if (tid < o) { r1[tid] += r1[tid + o]; r2[tid] += r2[tid + o]; }
        __syncthreads();
    }
    float mean = r1[0] * (1.0f / D_);
    float var = r2[0] * (1.0f / D_) - mean * mean;
    float inv = rsqrtf(var + 1e-5f);
    size_t bfrow = strided_bf ? (size_t)(b * T_ + pos) : (size_t)r;
#pragma unroll
    for (int i = tid; i < D_; i += 256) {
        float y = (x[i] - mean) * inv * sc[i] + bi[i];
        if (outf) outf[(size_t)(b * T_ + pos) * D_ + i] = y;
        outbf[bfrow * D_ + i] = f2bf(y);
    }
}

// ---------------- MFMA GEMM: C[M,N] = A[M,K](bf16) @ Bt[N,K]^T(bf16) ----------------
// MODE 1: qkv scatter -> bf16 q (compact) / k,v caches (strided)
// MODE 2: residual add fp32; MODE 3: gelu -> bf16
template <int MODE>
__global__ __launch_bounds__(256) void k_mgemm(const unsigned short* __restrict__ Abf,
        const unsigned short* __restrict__ Bt, const float* __restrict__ bias,
        float* __restrict__ o0, unsigned short* __restrict__ u0,
        unsigned short* __restrict__ u1, unsigned short* __restrict__ u2,
        int M, int N, int K, int c0, int range) {
    __shared__ short8 As_v[512];
    __shared__ short8 Bs_v[512];
    int tid = threadIdx.x;
    int lane = tid & 63, w = tid >> 6;
    int quad = lane >> 4, l15 = lane & 15;
    int row0 = blockIdx.y * 128, col0 = blockIdx.x * 128;
    int rh = (w >> 1) * 64, ch = (w & 1) * 64;

    int cA0 = w * 128 + lane, cA1 = cA0 + 64;
    int rA0 = cA0 & 127, kgA0 = cA0 >> 7;
    int rA1 = cA1 & 127, kgA1 = cA1 >> 7;
    int rowA0 = row0 + rA0; if (rowA0 >= M) rowA0 = M - 1;
    int rowA1 = row0 + rA1; if (rowA1 >= M) rowA1 = M - 1;
    const unsigned short* ga0 = Abf + (size_t)rowA0 * K + kgA0 * 8;
    const unsigned short* ga1 = Abf + (size_t)rowA1 * K + kgA1 * 8;
    const unsigned short* gb0 = Bt + (size_t)(col0 + rA0) * K + kgA0 * 8;
    const unsigned short* gb1 = Bt + (size_t)(col0 + rA1) * K + kgA1 * 8;

    floatx4 acc[4][4];
#pragma unroll
    for (int i = 0; i < 4; i++)
#pragma unroll
        for (int j = 0; j < 4; j++)
#pragma unroll
            for (int k = 0; k < 4; k++) acc[i][j][k] = 0.f;

    int iters = K >> 5;
    for (int it = 0; it < iters; ++it) {
        __syncthreads();
        gld_lds16(&As_v[w * 128],      ga0);
        gld_lds16(&As_v[w * 128 + 64], ga1);
        gld_lds16(&Bs_v[w * 128],      gb0);
        gld_lds16(&Bs_v[w * 128 + 64], gb1);
        ga0 += 32; ga1 += 32; gb0 += 32; gb1 += 32;
        __syncthreads();
        short8 af[4], bfv[4];
#pragma unroll
        for (int mi = 0; mi < 4; mi++) af[mi] = As_v[quad * 128 + rh + mi * 16 + l15];
#pragma unroll
        for (int nj = 0; nj < 4; nj++) bfv[nj] = Bs_v[quad * 128 + ch + nj * 16 + l15];
#pragma unroll
        for (int mi = 0; mi < 4; mi++)
#pragma unroll
            for (int nj = 0; nj < 4; nj++)
                acc[mi][nj] = __builtin_amdgcn_mfma_f32_16x16x32_bf16(af[mi], bfv[nj], acc[mi][nj], 0, 0, 0);
    }

#pragma unroll
    for (int mi = 0; mi < 4; mi++)
#pragma unroll
        for (int reg = 0; reg < 4; reg++) {
            int r = row0 + rh + mi * 16 + quad * 4 + reg;
            if (r >= M) continue;
            int b = r / range, pos = c0 + r % range;
#pragma unroll
            for (int nj = 0; nj < 4; nj++) {
                int n = col0 + ch + nj * 16 + l15;
                float v = acc[mi][nj][reg] + bias[n];
                if constexpr (MODE == 1) {
                    if (n < 1024) u0[(size_t)r * 1024 + n] = f2bf(v);
                    else if (n < 2048) u1[(size_t)(b * T_ + pos) * 1024 + (n - 1024)] = f2bf(v);
                    else u2[(size_t)(b * T_ + pos) * 1024 + (n - 2048)] = f2bf(v);
                } else if constexpr (MODE == 2) {
                    o0[(size_t)(b * T_ + pos) * D_ + n] += v;
                } else if constexpr (MODE == 3) {
                    u0[(size_t)r * N + n] = f2bf(gelu_tanh(v));
                }
            }
        }
}

// ---------------- V transpose into global vtc[(b*16+h)*64+d][T] ----------------
__global__ __launch_bounds__(256) void k_vtrans(const unsigned short* __restrict__ vcbf,
        unsigned short* __restrict__ vtc, int c0, int range) {
    __shared__ unsigned short ts[64][72];
    int pt = blockIdx.x, h = blockIdx.y, b = blockIdx.z;
    int t = threadIdx.x;
#pragma unroll
    for (int i = 0; i < 2; i++) {
        int idx = t + i * 256;
        int p = idx >> 3, c8 = idx & 7;
        int pos = c0 + pt * 64 + p;
        if (pos < c0 + range) {
            short8 v = *(const short8*)&vcbf[(size_t)(b * T_ + pos) * D_ + h * 64 + c8 * 8];
            *(short8*)&ts[p][c8 * 8] = v;
        }
    }
    __syncthreads();
#pragma unroll
    for (int i = 0; i < 2; i++) {
        int idx = t + i * 256;
        int d = idx >> 3, p8 = idx & 7;
        unsigned short tmp[8];
#pragma unroll
        for (int j = 0; j < 8; j++) tmp[j] = ts[p8 * 8 + j][d];
        int pos0 = c0 + pt * 64 + p8 * 8;
        size_t rb = (size_t)((b * 16 + h) * 64 + d) * T_;
        if (pos0 + 7 < c0 + range) {
            *(short8*)&vtc[rb + pos0] = *(short8*)tmp;
        } else {
            for (int j = 0; j < 8; j++)
                if (pos0 + j < c0 + range) vtc[rb + pos0 + j] = tmp[j];
        }
    }
}

// ---------------- barrier-free MFMA flash attention ----------------
// grid (ceil(range/64), H, B), block 256 = 4 independent waves, 16 queries/wave
__global__ __launch_bounds__(256) void k_fattn(const unsigned short* __restrict__ qbf,
        const unsigned short* __restrict__ kcbf, const unsigned short* __restrict__ vtc,
        unsigned short* __restrict__ ctxbf, int c0, int range) {
    __shared__ unsigned short pw[4][16][72];
    int tid = threadIdx.x;
    int w = tid >> 6, lane = tid & 63, quad = lane >> 4, l15 = lane & 15;
    int qt = blockIdx.x, h = blockIdx.y, b = blockIdx.z;
    int q0 = qt * 64 + w * 16;
    if (q0 >= range) return;                 // no barriers in this kernel -> safe
    int qtop = q0 + 15; if (qtop >= range) qtop = range - 1;
    int nkt = (c0 + qtop) / 64 + 1;

    int qrow = q0 + l15; if (qrow >= range) qrow = range - 1;
    const unsigned short* qp = qbf + (size_t)(b * range + qrow) * D_ + h * 64 + quad * 8;
    short8 aq0 = *(const short8*)qp;
    short8 aq1 = *(const short8*)(qp + 32);

    floatx4 oacc[4];
#pragma unroll
    for (int dg = 0; dg < 4; dg++)
#pragma unroll
        for (int r = 0; r < 4; r++) oacc[dg][r] = 0.f;
    float m_r[4] = {-1e30f, -1e30f, -1e30f, -1e30f};
    float l_r[4] = {0.f, 0.f, 0.f, 0.f};

    const unsigned short* kb_p = kcbf + (size_t)b * T_ * D_ + h * 64 + quad * 8;
    const unsigned short* vb_p = vtc + (size_t)((b * 16 + h) * 64 + l15) * T_ + quad * 8;

    for (int kt = 0; kt < nkt; kt++) {
        int kb = kt * 64;
        floatx4 s[4];
#pragma unroll
        for (int g = 0; g < 4; g++) {
            const unsigned short* kp = kb_p + (size_t)(kb + g * 16 + l15) * D_;
            short8 bk0 = *(const short8*)kp;
            short8 bk1 = *(const short8*)(kp + 32);
            floatx4 z; z[0] = 0.f; z[1] = 0.f; z[2] = 0.f; z[3] = 0.f;
            z = __builtin_amdgcn_mfma_f32_16x16x32_bf16(aq0, bk0, z, 0, 0, 0);
            s[g] = __builtin_amdgcn_mfma_f32_16x16x32_bf16(aq1, bk1, z, 0, 0, 0);
        }
#pragma unroll
        for (int r = 0; r < 4; r++) {
            int qpos = c0 + q0 + quad * 4 + r;
            float mx = -1e30f;
#pragma unroll
            for (int g = 0; g < 4; g++) {
                int kpos = kb + g * 16 + l15;
                float sv = (kpos <= qpos) ? s[g][r] * 0.125f : -1e30f;
                s[g][r] = sv; mx = fmaxf(mx, sv);
            }
            mx = fmaxf(mx, __shfl_xor(mx, 1));
            mx = fmaxf(mx, __shfl_xor(mx, 2));
            mx = fmaxf(mx, __shfl_xor(mx, 4));
            mx = fmaxf(mx, __shfl_xor(mx, 8));
            float mn = fmaxf(m_r[r], mx);
            float alpha = __expf(m_r[r] - mn);
            m_r[r] = mn;
            float ls = 0.f;
#pragma unroll
            for (int g = 0; g < 4; g++) {
                float p = __expf(s[g][r] - mn);
                s[g][r] = p; ls += p;
            }
            ls += __shfl_xor(ls, 1);
            ls += __shfl_xor(ls, 2);
            ls += __shfl_xor(ls, 4);
            ls += __shfl_xor(ls, 8);
            l_r[r] = l_r[r] * alpha + ls;
#pragma unroll
            for (int dg = 0; dg < 4; dg++) oacc[dg][r] *= alpha;
        }
        // P (C-layout) -> LDS -> A-layout fragments (wave-private, no barrier)
#pragma unroll
        for (int g = 0; g < 4; g++)
#pragma unroll
            for (int r = 0; r < 4; r++)
                pw[w][quad * 4 + r][g * 16 + l15] = f2bf(s[g][r]);
        short8 ap0 = *(const short8*)&pw[w][l15][quad * 8];
        short8 ap1 = *(const short8*)&pw[w][l15][32 + quad * 8];
#pragma unroll
        for (int dg = 0; dg < 4; dg++) {
            const unsigned short* vp = vb_p + (size_t)(dg * 16) * T_ + kb;
            short8 bv0 = *(const short8*)vp;
            short8 bv1 = *(const short8*)(vp + 32);
            oacc[dg] = __builtin_amdgcn_mfma_f32_16x16x32_bf16(ap0, bv0, oacc[dg], 0, 0, 0);
            oacc[dg] = __builtin_amdgcn_mfma_f32_16x16x32_bf16(ap1, bv1, oacc[dg], 0, 0, 0);
        }
    }
#pragma unroll
    for (int dg = 0; dg < 4; dg++)
#pragma unroll
        for (int r = 0; r < 4; r++) {
            int qloc = q0 + quad * 4 + r;
            if (qloc < range)
                ctxbf[(size_t)(b * range + qloc) * D_ + h * 64 + dg * 16 + l15] =
                    f2bf(oacc[dg][r] / l_r[r]);
        }
}

// ---------------- latent vec fills ----------------
__global__ void k_latent0(const float* __restrict__ hid, const float* __restrict__ lw,
                          float* __restrict__ embeds) {
    int idx = blockIdx.x * 256 + threadIdx.x;
    if (idx >= B_ * D_) return;
    int b = idx / D_, d = idx % D_;
    float w0 = lw[0], w1 = lw[1], w2 = lw[2];
    float mx = fmaxf(w0, fmaxf(w1, w2));
    float e0 = __expf(w0 - mx), e1 = __expf(w1 - mx), e2 = __expf(w2 - mx);
    float inv = 1.0f / (e0 + e1 + e2);
    float v = (e0 * hid[(size_t)(b * T_ + 509) * D_ + d] +
               e1 * hid[(size_t)(b * T_ + 510) * D_ + d] +
               e2 * hid[(size_t)(b * T_ + 511) * D_ + d]) * inv;
    embeds[(size_t)(b * T_ + 512) * D_ + d] = v;
}

__global__ void k_latent1(const float* __restrict__ hid, float* __restrict__ embeds, int tok) {
    int idx = blockIdx.x * 256 + threadIdx.x;
    if (idx >= B_ * D_) return;
    int b = idx / D_, d = idx % D_;
    embeds[(size_t)(b * T_ + tok) * D_ + d] = hid[(size_t)(b * T_ + tok - 1) * D_ + d];
}

// ---------------- loss MFMA GEMM: logits chunk + fused (max,sumexp,label) ----------------
__global__ __launch_bounds__(256) void k_loss1m(const unsigned short* __restrict__ hidbf,
        const unsigned short* __restrict__ embedbf, const int* __restrict__ labels,
        float* __restrict__ partm, float* __restrict__ parts, float* __restrict__ llogit) {
    __shared__ short8 As_v[512];
    __shared__ short8 Bs_v[512];
    __shared__ int lds_lab[128];
    __shared__ float lds_pm[128][2];
    __shared__ float lds_ps[128][2];
    int tid = threadIdx.x;
    int lane = tid & 63, w = tid >> 6;
    int quad = lane >> 4, l15 = lane & 15;
    int chunk = blockIdx.x;
    int row0 = blockIdx.y * 128, v0 = chunk * 128;
    int rh = (w >> 1) * 64, ch = (w & 1) * 64;

    if (tid < 128) {
        int tok = row0 + tid;
        lds_lab[tid] = (tok < NTOK) ? labels[tok + 1 + (tok >= 1023)] : -1;
    }

    int cA0 = w * 128 + lane, cA1 = cA0 + 64;
    int rA0 = cA0 & 127, kgA0 = cA0 >> 7;
    int rA1 = cA1 & 127, kgA1 = cA1 >> 7;
    int tokA0 = row0 + rA0; if (tokA0 >= NTOK) tokA0 = NTOK - 1;
    int tokA1 = row0 + rA1; if (tokA1 >= NTOK) tokA1 = NTOK - 1;
    const unsigned short* ga0 = hidbf + (size_t)(tokA0 + (tokA0 >= 1023)) * D_ + kgA0 * 8;
    const unsigned short* ga1 = hidbf + (size_t)(tokA1 + (tokA1 >= 1023)) * D_ + kgA1 * 8;
    const unsigned short* gb0 = embedbf + (size_t)(v0 + rA0) * D_ + kgA0 * 8;
    const unsigned short* gb1 = embedbf + (size_t)(v0 + rA1) * D_ + kgA1 * 8;

    floatx4 acc[4][4];
#pragma unroll
    for (int i = 0; i < 4; i++)
#pragma unroll
        for (int j = 0; j < 4; j++)
#pragma unroll
            for (int k = 0; k < 4; k++) acc[i][j][k] = 0.f;

    for (int it = 0; it < D_ / 32; ++it) {
        __syncthreads();
        gld_lds16(&As_v[w * 128],      ga0);
        gld_lds16(&As_v[w * 128 + 64], ga1);
        gld_lds16(&Bs_v[w * 128],      gb0);
        gld_lds16(&Bs_v[w * 128 + 64], gb1);
        ga0 += 32; ga1 += 32; gb0 += 32; gb1 += 32;
        __syncthreads();
        short8 af[4], bfv[4];
#pragma unroll
        for (int mi = 0; mi < 4; mi++) af[mi] = As_v[quad * 128 + rh + mi * 16 + l15];
#pragma unroll
        for (int nj = 0; nj < 4; nj++) bfv[nj] = Bs_v[quad * 128 + ch + nj * 16 + l15];
#pragma unroll
        for (int mi = 0; mi < 4; mi++)
#pragma unroll
            for (int nj = 0; nj < 4; nj++)
                acc[mi][nj] = __builtin_amdgcn_mfma_f32_16x16x32_bf16(af[mi], bfv[nj], acc[mi][nj], 0, 0, 0);
    }

#pragma unroll
    for (int mi = 0; mi < 4; mi++)
#pragma unroll
        for (int reg = 0; reg < 4; reg++) {
            int rloc = rh + mi * 16 + quad * 4 + reg;
            int lab = lds_lab[rloc];
            float vm = -1e30f;
#pragma unroll
            for (int nj = 0; nj < 4; nj++) {
                float v = acc[mi][nj][reg];
                int vcol = v0 + ch + nj * 16 + l15;
                if (vcol == lab) llogit[row0 + rloc] = v;
                vm = fmaxf(vm, v);
            }
            for (int off = 1; off < 16; off <<= 1) vm = fmaxf(vm, __shfl_xor(vm, off));
            float ss = 0.f;
#pragma unroll
            for (int nj = 0; nj < 4; nj++) ss += __expf(acc[mi][nj][reg] - vm);
            for (int off = 1; off < 16; off <<= 1) ss += __shfl_xor(ss, off);
            if (l15 == 0) { lds_pm[rloc][ch >> 6] = vm; lds_ps[rloc][ch >> 6] = ss; }
        }
    __syncthreads();
    if (tid < 128) {
        int tok = row0 + tid;
        if (tok < NTOK) {
            float m0 = lds_pm[tid][0], m1 = lds_pm[tid][1];
            float M = fmaxf(m0, m1);
            float S = lds_ps[tid][0] * __expf(m0 - M) + lds_ps[tid][1] * __expf(m1 - M);
            partm[(size_t)chunk * NTOK + tok] = M;
            parts[(size_t)chunk * NTOK + tok] = S;
        }
    }
}

// ---------------- loss combine ----------------
__global__ void k_loss2a(const float* __restrict__ partm, const float* __restrict__ parts,
                         const float* __restrict__ ll, float* __restrict__ nll) {
    int tok = blockIdx.x * 256 + threadIdx.x;
    if (tok >= NTOK) return;
    float M = -1e30f;
    for (int c = 0; c < NCH; c++) M = fmaxf(M, partm[(size_t)c * NTOK + tok]);
    float S = 0.f;
    for (int c = 0; c < NCH; c++)
        S += parts[(size_t)c * NTOK + tok] * __expf(partm[(size_t)c * NTOK + tok] - M);
    nll[tok] = logf(S) + M - ll[tok];
}

__global__ __launch_bounds__(256) void k_loss2b(const float* __restrict__ nll, float* __restrict__ out) {
    __shared__ float red[256];
    int tid = threadIdx.x;
    float s = 0.f;
    for (int i = tid; i < NTOK; i += 256) s += nll[i];
    red[tid] = s; __syncthreads();
    for (int o = 128; o > 0; o >>= 1) {
        if (tid < o) red[tid] += red[tid + o];
        __syncthreads();
    }
    if (tid == 0) out[0] = red[0] / (float)NTOK;
}

// ---------------- host ----------------
extern "C" void kernel_launch(void* const* d_in, const int* in_sizes, int n_in,
                              void* d_out, int out_size, void* d_ws, size_t ws_size,
                              hipStream_t stream) {
    const int*   input_ids = (const int*)d_in[0];
    const int*   labels    = (const int*)d_in[2];
    const float* embed     = (const float*)d_in[4];
    const float* Wpos      = (const float*)d_in[5];
    const float* Wqkv      = (const float*)d_in[6];
    const float* bqkv      = (const float*)d_in[7];
    const float* Aq        = (const float*)d_in[8];
    const float* Bq        = (const float*)d_in[9];
    const float* Wo        = (const float*)d_in[10];
    const float* bo        = (const float*)d_in[11];
    const float* Ao        = (const float*)d_in[12];
    const float* Bo        = (const float*)d_in[13];
    const float* W1        = (const float*)d_in[14];
    const float* b1        = (const float*)d_in[15];
    const float* W2        = (const float*)d_in[16];
    const float* b2        = (const float*)d_in[17];
    const float* ln1_s     = (const float*)d_in[18];
    const float* ln1_b     = (const float*)d_in[19];
    const float* ln2_s     = (const float*)d_in[20];
    const float* ln2_b     = (const float*)d_in[21];
    const float* lnf_s     = (const float*)d_in[22];
    const float* lnf_b     = (const float*)d_in[23];
    const float* latent_w  = (const float*)d_in[24];

    char* base = (char*)d_ws;
    size_t off = 0;
    auto alloc = [&](size_t bytes) { void* p = base + off; off += (bytes + 255) & ~255ULL; return p; };

    float* embeds  = (float*)alloc((size_t)B_ * T_ * D_ * 4);
    float* hbuf    = (float*)alloc((size_t)B_ * T_ * D_ * 4);
    float* hidbuf  = (float*)alloc((size_t)B_ * T_ * D_ * 4);
    float* partm   = (float*)alloc((size_t)NCH * NTOK * 4);
    float* parts_  = (float*)alloc((size_t)NCH * NTOK * 4);
    float* llogit  = (float*)alloc((size_t)NTOK * 4);
    float* nllbuf  = (float*)alloc((size_t)NTOK * 4);
    unsigned short* wqkvT  = (unsigned short*)alloc((size_t)3072 * 1024 * 2);
    unsigned short* woT    = (unsigned short*)alloc((size_t)1024 * 1024 * 2);
    unsigned short* W1T    = (unsigned short*)alloc((size_t)4096 * 1024 * 2);
    unsigned short* W2T    = (unsigned short*)alloc((size_t)1024 * 4096 * 2);
    unsigned short* embedbf = (unsigned short*)alloc((size_t)V_ * D_ * 2);
    unsigned short* hidbf  = (unsigned short*)alloc((size_t)B_ * T_ * D_ * 2);
    unsigned short* abf    = (unsigned short*)alloc((size_t)1024 * D_ * 2);
    unsigned short* ctxbf  = (unsigned short*)alloc((size_t)1024 * D_ * 2);
    unsigned short* ffbw   = (unsigned short*)alloc((size_t)1024 * DFF_ * 2);
    unsigned short* qbf    = (unsigned short*)alloc((size_t)1024 * D_ * 2);
    unsigned short* kcbf   = (unsigned short*)alloc((size_t)B_ * T_ * D_ * 2);
    unsigned short* vcbf   = (unsigned short*)alloc((size_t)B_ * T_ * D_ * 2);
    unsigned short* vtc    = (unsigned short*)alloc((size_t)B_ * H_ * DH_ * T_ * 2);

    // weight prep (transpose + LoRA merge + bf16)
    k_prep_w<<<dim3(3072 / 64, 1024 / 64), 256, 0, stream>>>(Wqkv, Aq, Bq, wqkvT, 1024, 3072, 1);
    k_prep_w<<<dim3(1024 / 64, 1024 / 64), 256, 0, stream>>>(Wo, Ao, Bo, woT, 1024, 1024, 1);
    k_prep_w<<<dim3(4096 / 64, 1024 / 64), 256, 0, stream>>>(W1, nullptr, nullptr, W1T, 1024, 4096, 0);
    k_prep_w<<<dim3(1024 / 64, 4096 / 64), 256, 0, stream>>>(W2, nullptr, nullptr, W2T, 4096, 1024, 0);
    k_f2bf<<<(V_ * D_ / 4 + 255) / 256, 256, 0, stream>>>(embed, embedbf, V_ * D_ / 4);
    k_embed_gather<<<B_ * T_, 256, 0, stream>>>(input_ids, embed, embeds);

    auto run_pass = [&](int c0, int c1) {
        int range = c1 - c0;
        int Mr = B_ * range;
        int gy = (Mr + 127) / 128;
        int qt = (range + 63) / 64;
        k_hinit<<<Mr, 256, 0, stream>>>(embeds, Wpos, hbuf, c0, range);
        k_ln<<<Mr, 256, 0, stream>>>(hbuf, ln1_s, ln1_b, nullptr, abf, c0, range, 0);
        k_mgemm<1><<<dim3(3072 / 128, gy), 256, 0, stream>>>(abf, wqkvT, bqkv, nullptr, qbf, kcbf, vcbf,
                                                             Mr, 3072, 1024, c0, range);
        k_vtrans<<<dim3(qt, H_, B_), 256, 0, stream>>>(vcbf, vtc, c0, range);
        k_fattn<<<dim3(qt, H_, B_), 256, 0, stream>>>(qbf, kcbf, vtc, ctxbf, c0, range);
        k_mgemm<2><<<dim3(1024 / 128, gy), 256, 0, stream>>>(ctxbf, woT, bo, hbuf, nullptr, nullptr, nullptr,
                                                             Mr, 1024, 1024, c0, range);
        k_ln<<<Mr, 256, 0, stream>>>(hbuf, ln2_s, ln2_b, nullptr, abf, c0, range, 0);
        k_mgemm<3><<<dim3(4096 / 128, gy), 256, 0, stream>>>(abf, W1T, b1, nullptr, ffbw, nullptr, nullptr,
                                                             Mr, 4096, 1024, c0, range);
        k_mgemm<2><<<dim3(1024 / 128, gy), 256, 0, stream>>>(ffbw, W2T, b2, hbuf, nullptr, nullptr, nullptr,
                                                             Mr, 1024, 4096, c0, range);
        k_ln<<<Mr, 256, 0, stream>>>(hbuf, lnf_s, lnf_b, hidbuf, hidbf, c0, range, 1);
    };

    run_pass(0, 512);
    k_latent0<<<(B_ * D_ + 255) / 256, 256, 0, stream>>>(hidbuf, latent_w, embeds);
    run_pass(512, 513);
    k_latent1<<<(B_ * D_ + 255) / 256, 256, 0, stream>>>(hidbuf, embeds, 513);
    run_pass(513, 514);
    k_latent1<<<(B_ * D_ + 255) / 256, 256, 0, stream>>>(hidbuf, embeds, 514);
    run_pass(514, 515);
    k_latent1<<<(B_ * D_ + 255) / 256, 256, 0, stream>>>(hidbuf, embeds, 515);
    run_pass(515, 1024);

    // loss
    k_loss1m<<<dim3(NCH, (NTOK + 127) / 128), 256, 0, stream>>>(hidbf, embedbf, labels, partm, parts_, llogit);
    k_loss2a<<<(NTOK + 255) / 256, 256, 0, stream>>>(partm, parts_, llogit, nllbuf);
    k_loss2b<<<1, 256, 0, stream>>>(nllbuf, (float*)d_out);
}

// Round 4
// 1558.732 us; speedup vs baseline: 4.5550x; 1.3213x over previous
//
#include <hip/hip_runtime.h>
#include <math.h>

#define B_   2
#define T_   1024
#define D_   1024
#define H_   16
#define DH_  64
#define DFF_ 4096
#define V_   32000
#define NTOK 2046      // B*(T-1)
#define NCH  250       // V_/128 vocab chunks for loss partials

typedef __attribute__((ext_vector_type(8))) short short8;
typedef __attribute__((ext_vector_type(4))) float floatx4;

__device__ __forceinline__ unsigned short f2bf(float x) {
    unsigned int u = __float_as_uint(x);
    unsigned int r = (u + 0x7fffu + ((u >> 16) & 1u)) >> 16;
    return (unsigned short)r;
}

__device__ __forceinline__ void gld_lds16(void* lds, const void* g) {
    __builtin_amdgcn_global_load_lds(
        (const __attribute__((address_space(1))) void*)g,
        (__attribute__((address_space(3))) void*)lds, 16, 0, 0);
}

__device__ __forceinline__ float gelu_tanh(float x) {
    float x3 = x * x * x;
    return 0.5f * x * (1.0f + tanhf(0.7978845608028654f * (x + 0.044715f * x3)));
}

// ---------------- weight prep: out[n*K+k] = bf16(W[k*N+n] + 2*(A@Bm)[k,n]) ----------------
__global__ __launch_bounds__(256) void k_prep_w(const float* __restrict__ W,
        const float* __restrict__ A, const float* __restrict__ Bm,
        unsigned short* __restrict__ out, int K, int N, int lora) {
    __shared__ float t[64][65];
    int n0 = blockIdx.x * 64, k0 = blockIdx.y * 64;
    int tid = threadIdx.x;
    int nn = tid & 63, kb = tid >> 6;
    for (int i = 0; i < 16; i++) {
        int kk = kb * 16 + i;
        float v = W[(size_t)(k0 + kk) * N + n0 + nn];
        if (lora) {
            float s = 0.f;
#pragma unroll
            for (int r = 0; r < 8; r++) s += A[(k0 + kk) * 8 + r] * Bm[r * N + n0 + nn];
            v += 2.0f * s;
        }
        t[kk][nn] = v;
    }
    __syncthreads();
    int kk2 = tid & 63, nb = tid >> 6;
    for (int j = 0; j < 16; j++) {
        int nn2 = nb * 16 + j;
        out[(size_t)(n0 + nn2) * K + k0 + kk2] = f2bf(t[kk2][nn2]);
    }
}

// ---------------- fp32 -> bf16 bulk convert ----------------
__global__ void k_f2bf(const float* __restrict__ in, unsigned short* __restrict__ out, int n4) {
    int i = blockIdx.x * 256 + threadIdx.x;
    if (i >= n4) return;
    float4 v = ((const float4*)in)[i];
    ushort4 o;
    o.x = f2bf(v.x); o.y = f2bf(v.y); o.z = f2bf(v.z); o.w = f2bf(v.w);
    ((ushort4*)out)[i] = o;
}

// ---------------- embedding gather ----------------
__global__ void k_embed_gather(const int* __restrict__ ids, const float* __restrict__ embed,
                               float* __restrict__ embeds) {
    int bt = blockIdx.x;
    int d4 = threadIdx.x;
    int id = ids[bt];
    ((float4*)embeds)[(size_t)bt * 256 + d4] = ((const float4*)embed)[(size_t)id * 256 + d4];
}

// ---------------- LayerNorm. If embeds!=null: x = embeds+Wpos (writes hout); else x = in. ----------------
__global__ __launch_bounds__(256) void k_ln(const float* __restrict__ in,
                                            const float* __restrict__ embeds, const float* __restrict__ Wpos,
                                            const float* __restrict__ sc, const float* __restrict__ bi,
                                            float* __restrict__ hout, float* __restrict__ outf,
                                            unsigned short* __restrict__ outbf,
                                            int c0, int range, int strided_bf) {
    int r = blockIdx.x;
    int b = r / range, pos = c0 + r % range;
    size_t rowoff = (size_t)(b * T_ + pos) * D_;
    int tid = threadIdx.x;
    float xv[4];
    if (embeds) {
#pragma unroll
        for (int j = 0; j < 4; j++) {
            int i = tid + j * 256;
            xv[j] = embeds[rowoff + i] + Wpos[(size_t)pos * D_ + i];
            hout[rowoff + i] = xv[j];
        }
    } else {
#pragma unroll
        for (int j = 0; j < 4; j++) xv[j] = in[rowoff + tid + j * 256];
    }
    float s1 = 0.f, s2 = 0.f;
#pragma unroll
    for (int j = 0; j < 4; j++) { s1 += xv[j]; s2 += xv[j] * xv[j]; }
    __shared__ float r1[256], r2[256];
    r1[tid] = s1; r2[tid] = s2; __syncthreads();
    for (int o = 128; o > 0; o >>= 1) {
        if (tid < o) { r1[tid] += r1[tid + o]; r2[tid] += r2[tid + o]; }
        __syncthreads();
    }
    float mean = r1[0] * (1.0f / D_);
    float var = r2[0] * (1.0f / D_) - mean * mean;
    float inv = rsqrtf(var + 1e-5f);
    size_t bfrow = strided_bf ? (size_t)(b * T_ + pos) : (size_t)r;
#pragma unroll
    for (int j = 0; j < 4; j++) {
        int i = tid + j * 256;
        float y = (xv[j] - mean) * inv * sc[i] + bi[i];
        if (outf) outf[rowoff + i] = y;
        outbf[bfrow * D_ + i] = f2bf(y);
    }
}

// ---------------- MFMA GEMM: C[M,N] = A[M,K](bf16) @ Bt[N,K]^T(bf16) ----------------
// MODE 1: qkv scatter -> bf16 q / k,v caches. MODE 2: split-K atomic residual add fp32.
// MODE 3: gelu -> bf16. grid.z = K segments (MODE 2 only).
template <int MODE>
__global__ __launch_bounds__(256) void k_mgemm(const unsigned short* __restrict__ Abf,
        const unsigned short* __restrict__ Bt, const float* __restrict__ bias,
        float* __restrict__ o0, unsigned short* __restrict__ u0,
        unsigned short* __restrict__ u1, unsigned short* __restrict__ u2,
        int M, int N, int K, int c0, int range, int ksegs) {
    __shared__ short8 As_v[512];
    __shared__ short8 Bs_v[512];
    int tid = threadIdx.x;
    int lane = tid & 63, w = tid >> 6;
    int quad = lane >> 4, l15 = lane & 15;
    int row0 = blockIdx.y * 128, col0 = blockIdx.x * 128;
    int kseg = blockIdx.z;
    int Klen = K / ksegs;
    int ksoff = kseg * Klen;
    int rh = (w >> 1) * 64, ch = (w & 1) * 64;

    int cA0 = w * 128 + lane, cA1 = cA0 + 64;
    int rA0 = cA0 & 127, kgA0 = cA0 >> 7;
    int rA1 = cA1 & 127, kgA1 = cA1 >> 7;
    int rowA0 = row0 + rA0; if (rowA0 >= M) rowA0 = M - 1;
    int rowA1 = row0 + rA1; if (rowA1 >= M) rowA1 = M - 1;
    const unsigned short* ga0 = Abf + (size_t)rowA0 * K + ksoff + kgA0 * 8;
    const unsigned short* ga1 = Abf + (size_t)rowA1 * K + ksoff + kgA1 * 8;
    const unsigned short* gb0 = Bt + (size_t)(col0 + rA0) * K + ksoff + kgA0 * 8;
    const unsigned short* gb1 = Bt + (size_t)(col0 + rA1) * K + ksoff + kgA1 * 8;

    floatx4 acc[4][4];
#pragma unroll
    for (int i = 0; i < 4; i++)
#pragma unroll
        for (int j = 0; j < 4; j++)
#pragma unroll
            for (int k = 0; k < 4; k++) acc[i][j][k] = 0.f;

    int iters = Klen >> 5;
    for (int it = 0; it < iters; ++it) {
        __syncthreads();
        gld_lds16(&As_v[w * 128],      ga0);
        gld_lds16(&As_v[w * 128 + 64], ga1);
        gld_lds16(&Bs_v[w * 128],      gb0);
        gld_lds16(&Bs_v[w * 128 + 64], gb1);
        ga0 += 32; ga1 += 32; gb0 += 32; gb1 += 32;
        __syncthreads();
        short8 af[4], bfv[4];
#pragma unroll
        for (int mi = 0; mi < 4; mi++) af[mi] = As_v[quad * 128 + rh + mi * 16 + l15];
#pragma unroll
        for (int nj = 0; nj < 4; nj++) bfv[nj] = Bs_v[quad * 128 + ch + nj * 16 + l15];
#pragma unroll
        for (int mi = 0; mi < 4; mi++)
#pragma unroll
            for (int nj = 0; nj < 4; nj++)
                acc[mi][nj] = __builtin_amdgcn_mfma_f32_16x16x32_bf16(af[mi], bfv[nj], acc[mi][nj], 0, 0, 0);
    }

#pragma unroll
    for (int mi = 0; mi < 4; mi++)
#pragma unroll
        for (int reg = 0; reg < 4; reg++) {
            int r = row0 + rh + mi * 16 + quad * 4 + reg;
            if (r >= M) continue;
            int b = r / range, pos = c0 + r % range;
#pragma unroll
            for (int nj = 0; nj < 4; nj++) {
                int n = col0 + ch + nj * 16 + l15;
                if constexpr (MODE == 1) {
                    float v = acc[mi][nj][reg] + bias[n];
                    if (n < 1024) u0[(size_t)r * 1024 + n] = f2bf(v);
                    else if (n < 2048) u1[(size_t)(b * T_ + pos) * 1024 + (n - 1024)] = f2bf(v);
                    else u2[(size_t)(b * T_ + pos) * 1024 + (n - 2048)] = f2bf(v);
                } else if constexpr (MODE == 2) {
                    float v = acc[mi][nj][reg] + (kseg == 0 ? bias[n] : 0.f);
                    atomicAdd(&o0[(size_t)(b * T_ + pos) * D_ + n], v);
                } else if constexpr (MODE == 3) {
                    float v = acc[mi][nj][reg] + bias[n];
                    u0[(size_t)r * N + n] = f2bf(gelu_tanh(v));
                }
            }
        }
}

// ---------------- V transpose into global vtc[(b*16+h)*64+d][T] ----------------
__global__ __launch_bounds__(256) void k_vtrans(const unsigned short* __restrict__ vcbf,
        unsigned short* __restrict__ vtc, int c0, int range) {
    __shared__ unsigned short ts[64][72];
    int pt = blockIdx.x, h = blockIdx.y, b = blockIdx.z;
    int t = threadIdx.x;
#pragma unroll
    for (int i = 0; i < 2; i++) {
        int idx = t + i * 256;
        int p = idx >> 3, c8 = idx & 7;
        int pos = c0 + pt * 64 + p;
        if (pos < c0 + range) {
            short8 v = *(const short8*)&vcbf[(size_t)(b * T_ + pos) * D_ + h * 64 + c8 * 8];
            *(short8*)&ts[p][c8 * 8] = v;
        }
    }
    __syncthreads();
#pragma unroll
    for (int i = 0; i < 2; i++) {
        int idx = t + i * 256;
        int d = idx >> 3, p8 = idx & 7;
        unsigned short tmp[8];
#pragma unroll
        for (int j = 0; j < 8; j++) tmp[j] = ts[p8 * 8 + j][d];
        int pos0 = c0 + pt * 64 + p8 * 8;
        size_t rb = (size_t)((b * 16 + h) * 64 + d) * T_;
        if (pos0 + 7 < c0 + range) {
            *(short8*)&vtc[rb + pos0] = *(short8*)tmp;
        } else {
            for (int j = 0; j < 8; j++)
                if (pos0 + j < c0 + range) vtc[rb + pos0 + j] = tmp[j];
        }
    }
}

// ---------------- barrier-free MFMA flash attention ----------------
__global__ __launch_bounds__(256) void k_fattn(const unsigned short* __restrict__ qbf,
        const unsigned short* __restrict__ kcbf, const unsigned short* __restrict__ vtc,
        unsigned short* __restrict__ ctxbf, int c0, int range) {
    __shared__ unsigned short pw[4][16][72];
    int tid = threadIdx.x;
    int w = tid >> 6, lane = tid & 63, quad = lane >> 4, l15 = lane & 15;
    int qt = blockIdx.x, h = blockIdx.y, b = blockIdx.z;
    int q0 = qt * 64 + w * 16;
    if (q0 >= range) return;                 // no barriers in this kernel -> safe
    int qtop = q0 + 15; if (qtop >= range) qtop = range - 1;
    int nkt = (c0 + qtop) / 64 + 1;

    int qrow = q0 + l15; if (qrow >= range) qrow = range - 1;
    const unsigned short* qp = qbf + (size_t)(b * range + qrow) * D_ + h * 64 + quad * 8;
    short8 aq0 = *(const short8*)qp;
    short8 aq1 = *(const short8*)(qp + 32);

    floatx4 oacc[4];
#pragma unroll
    for (int dg = 0; dg < 4; dg++)
#pragma unroll
        for (int r = 0; r < 4; r++) oacc[dg][r] = 0.f;
    float m_r[4] = {-1e30f, -1e30f, -1e30f, -1e30f};
    float l_r[4] = {0.f, 0.f, 0.f, 0.f};

    const unsigned short* kb_p = kcbf + (size_t)b * T_ * D_ + h * 64 + quad * 8;
    const unsigned short* vb_p = vtc + (size_t)((b * 16 + h) * 64 + l15) * T_ + quad * 8;

    for (int kt = 0; kt < nkt; kt++) {
        int kb = kt * 64;
        floatx4 s[4];
#pragma unroll
        for (int g = 0; g < 4; g++) {
            const unsigned short* kp = kb_p + (size_t)(kb + g * 16 + l15) * D_;
            short8 bk0 = *(const short8*)kp;
            short8 bk1 = *(const short8*)(kp + 32);
            floatx4 z; z[0] = 0.f; z[1] = 0.f; z[2] = 0.f; z[3] = 0.f;
            z = __builtin_amdgcn_mfma_f32_16x16x32_bf16(aq0, bk0, z, 0, 0, 0);
            s[g] = __builtin_amdgcn_mfma_f32_16x16x32_bf16(aq1, bk1, z, 0, 0, 0);
        }
#pragma unroll
        for (int r = 0; r < 4; r++) {
            int qpos = c0 + q0 + quad * 4 + r;
            float mx = -1e30f;
#pragma unroll
            for (int g = 0; g < 4; g++) {
                int kpos = kb + g * 16 + l15;
                float sv = (kpos <= qpos) ? s[g][r] * 0.125f : -1e30f;
                s[g][r] = sv; mx = fmaxf(mx, sv);
            }
            mx = fmaxf(mx, __shfl_xor(mx, 1));
            mx = fmaxf(mx, __shfl_xor(mx, 2));
            mx = fmaxf(mx, __shfl_xor(mx, 4));
            mx = fmaxf(mx, __shfl_xor(mx, 8));
            float mn = fmaxf(m_r[r], mx);
            float alpha = __expf(m_r[r] - mn);
            m_r[r] = mn;
            float ls = 0.f;
#pragma unroll
            for (int g = 0; g < 4; g++) {
                float p = __expf(s[g][r] - mn);
                s[g][r] = p; ls += p;
            }
            ls += __shfl_xor(ls, 1);
            ls += __shfl_xor(ls, 2);
            ls += __shfl_xor(ls, 4);
            ls += __shfl_xor(ls, 8);
            l_r[r] = l_r[r] * alpha + ls;
#pragma unroll
            for (int dg = 0; dg < 4; dg++) oacc[dg][r] *= alpha;
        }
#pragma unroll
        for (int g = 0; g < 4; g++)
#pragma unroll
            for (int r = 0; r < 4; r++)
                pw[w][quad * 4 + r][g * 16 + l15] = f2bf(s[g][r]);
        short8 ap0 = *(const short8*)&pw[w][l15][quad * 8];
        short8 ap1 = *(const short8*)&pw[w][l15][32 + quad * 8];
#pragma unroll
        for (int dg = 0; dg < 4; dg++) {
            const unsigned short* vp = vb_p + (size_t)(dg * 16) * T_ + kb;
            short8 bv0 = *(const short8*)vp;
            short8 bv1 = *(const short8*)(vp + 32);
            oacc[dg] = __builtin_amdgcn_mfma_f32_16x16x32_bf16(ap0, bv0, oacc[dg], 0, 0, 0);
            oacc[dg] = __builtin_amdgcn_mfma_f32_16x16x32_bf16(ap1, bv1, oacc[dg], 0, 0, 0);
        }
    }
#pragma unroll
    for (int dg = 0; dg < 4; dg++)
#pragma unroll
        for (int r = 0; r < 4; r++) {
            int qloc = q0 + quad * 4 + r;
            if (qloc < range)
                ctxbf[(size_t)(b * range + qloc) * D_ + h * 64 + dg * 16 + l15] =
                    f2bf(oacc[dg][r] / l_r[r]);
        }
}

// ---------------- latent vec fills ----------------
__global__ void k_latent0(const float* __restrict__ hid, const float* __restrict__ lw,
                          float* __restrict__ embeds) {
    int idx = blockIdx.x * 256 + threadIdx.x;
    if (idx >= B_ * D_) return;
    int b = idx / D_, d = idx % D_;
    float w0 = lw[0], w1 = lw[1], w2 = lw[2];
    float mx = fmaxf(w0, fmaxf(w1, w2));
    float e0 = __expf(w0 - mx), e1 = __expf(w1 - mx), e2 = __expf(w2 - mx);
    float inv = 1.0f / (e0 + e1 + e2);
    float v = (e0 * hid[(size_t)(b * T_ + 509) * D_ + d] +
               e1 * hid[(size_t)(b * T_ + 510) * D_ + d] +
               e2 * hid[(size_t)(b * T_ + 511) * D_ + d]) * inv;
    embeds[(size_t)(b * T_ + 512) * D_ + d] = v;
}

__global__ void k_latent1(const float* __restrict__ hid, float* __restrict__ embeds, int tok) {
    int idx = blockIdx.x * 256 + threadIdx.x;
    if (idx >= B_ * D_) return;
    int b = idx / D_, d = idx % D_;
    embeds[(size_t)(b * T_ + tok) * D_ + d] = hid[(size_t)(b * T_ + tok - 1) * D_ + d];
}

// ---------------- loss MFMA GEMM: 256x128 tile, fused (max,sumexp,label) ----------------
__global__ __launch_bounds__(256, 2) void k_loss1m(const unsigned short* __restrict__ hidbf,
        const unsigned short* __restrict__ embedbf, const int* __restrict__ labels,
        float* __restrict__ partm, float* __restrict__ parts, float* __restrict__ llogit) {
    __shared__ short8 As_v[1024];    // [kg 0..3][row 0..255]
    __shared__ short8 Bs_v[512];     // [kg 0..3][col 0..127]
    __shared__ int lds_lab[256];
    __shared__ float lds_pm[256][2];
    __shared__ float lds_ps[256][2];
    int tid = threadIdx.x;
    int lane = tid & 63, w = tid >> 6;
    int quad = lane >> 4, l15 = lane & 15;
    int chunk = blockIdx.x;
    int row0 = blockIdx.y * 256, v0 = chunk * 128;
    int rh = (w >> 1) * 128, ch = (w & 1) * 64;

    {
        int tok = row0 + tid;
        lds_lab[tid] = (tok < NTOK) ? labels[tok + 1 + (tok >= 1023)] : -1;
    }

    // A staging: thread stages row (w*64+lane) for kg=0..3
    int rowa = row0 + w * 64 + lane; if (rowa >= NTOK) rowa = NTOK - 1;
    const unsigned short* gA = hidbf + (size_t)(rowa + (rowa >= 1023)) * D_;
    // B staging: thread stages col ((w&1)*64+lane? no: (w&1)... ) derived below
    int colb = ((w * 64 + lane) & 127);
    int kgb = (w >> 1);
    const unsigned short* gB = embedbf + (size_t)(v0 + colb) * D_;

    floatx4 acc[8][4];
#pragma unroll
    for (int i = 0; i < 8; i++)
#pragma unroll
        for (int j = 0; j < 4; j++)
#pragma unroll
            for (int k = 0; k < 4; k++) acc[i][j][k] = 0.f;

    for (int it = 0; it < 32; ++it) {
        int k0 = it * 32;
        __syncthreads();
#pragma unroll
        for (int j = 0; j < 4; j++)
            gld_lds16(&As_v[j * 256 + w * 64], gA + k0 + j * 8);
#pragma unroll
        for (int j = 0; j < 2; j++)
            gld_lds16(&Bs_v[j * 256 + w * 64], gB + k0 + (j * 2 + kgb) * 8);
        __syncthreads();
        short8 bfv[4];
#pragma unroll
        for (int nj = 0; nj < 4; nj++) bfv[nj] = Bs_v[quad * 128 + ch + nj * 16 + l15];
#pragma unroll
        for (int mi = 0; mi < 8; mi++) {
            short8 af = As_v[quad * 256 + rh + mi * 16 + l15];
#pragma unroll
            for (int nj = 0; nj < 4; nj++)
                acc[mi][nj] = __builtin_amdgcn_mfma_f32_16x16x32_bf16(af, bfv[nj], acc[mi][nj], 0, 0, 0);
        }
    }

#pragma unroll
    for (int mi = 0; mi < 8; mi++)
#pragma unroll
        for (int reg = 0; reg < 4; reg++) {
            int rloc = rh + mi * 16 + quad * 4 + reg;
            int lab = lds_lab[rloc];
            float vm = -1e30f;
#pragma unroll
            for (int nj = 0; nj < 4; nj++) {
                float v = acc[mi][nj][reg];
                int vcol = v0 + ch + nj * 16 + l15;
                if (vcol == lab) llogit[row0 + rloc] = v;
                vm = fmaxf(vm, v);
            }
            for (int off = 1; off < 16; off <<= 1) vm = fmaxf(vm, __shfl_xor(vm, off));
            float ss = 0.f;
#pragma unroll
            for (int nj = 0; nj < 4; nj++) ss += __expf(acc[mi][nj][reg] - vm);
            for (int off = 1; off < 16; off <<= 1) ss += __shfl_xor(ss, off);
            if (l15 == 0) { lds_pm[rloc][w & 1] = vm; lds_ps[rloc][w & 1] = ss; }
        }
    __syncthreads();
    {
        int tok = row0 + tid;
        if (tok < NTOK) {
            float m0 = lds_pm[tid][0], m1 = lds_pm[tid][1];
            float M = fmaxf(m0, m1);
            float S = lds_ps[tid][0] * __expf(m0 - M) + lds_ps[tid][1] * __expf(m1 - M);
            partm[(size_t)chunk * NTOK + tok] = M;
            parts[(size_t)chunk * NTOK + tok] = S;
        }
    }
}

// ---------------- loss combine ----------------
__global__ void k_loss2a(const float* __restrict__ partm, const float* __restrict__ parts,
                         const float* __restrict__ ll, float* __restrict__ nll) {
    int tok = blockIdx.x * 256 + threadIdx.x;
    if (tok >= NTOK) return;
    float M = -1e30f;
    for (int c = 0; c < NCH; c++) M = fmaxf(M, partm[(size_t)c * NTOK + tok]);
    float S = 0.f;
    for (int c = 0; c < NCH; c++)
        S += parts[(size_t)c * NTOK + tok] * __expf(partm[(size_t)c * NTOK + tok] - M);
    nll[tok] = logf(S) + M - ll[tok];
}

__global__ __launch_bounds__(256) void k_loss2b(const float* __restrict__ nll, float* __restrict__ out) {
    __shared__ float red[256];
    int tid = threadIdx.x;
    float s = 0.f;
    for (int i = tid; i < NTOK; i += 256) s += nll[i];
    red[tid] = s; __syncthreads();
    for (int o = 128; o > 0; o >>= 1) {
        if (tid < o) red[tid] += red[tid + o];
        __syncthreads();
    }
    if (tid == 0) out[0] = red[0] / (float)NTOK;
}

// ---------------- host ----------------
extern "C" void kernel_launch(void* const* d_in, const int* in_sizes, int n_in,
                              void* d_out, int out_size, void* d_ws, size_t ws_size,
                              hipStream_t stream) {
    const int*   input_ids = (const int*)d_in[0];
    const int*   labels    = (const int*)d_in[2];
    const float* embed     = (const float*)d_in[4];
    const float* Wpos      = (const float*)d_in[5];
    const float* Wqkv      = (const float*)d_in[6];
    const float* bqkv      = (const float*)d_in[7];
    const float* Aq        = (const float*)d_in[8];
    const float* Bq        = (const float*)d_in[9];
    const float* Wo        = (const float*)d_in[10];
    const float* bo        = (const float*)d_in[11];
    const float* Ao        = (const float*)d_in[12];
    const float* Bo        = (const float*)d_in[13];
    const float* W1        = (const float*)d_in[14];
    const float* b1        = (const float*)d_in[15];
    const float* W2        = (const float*)d_in[16];
    const float* b2        = (const float*)d_in[17];
    const float* ln1_s     = (const float*)d_in[18];
    const float* ln1_b     = (const float*)d_in[19];
    const float* ln2_s     = (const float*)d_in[20];
    const float* ln2_b     = (const float*)d_in[21];
    const float* lnf_s     = (const float*)d_in[22];
    const float* lnf_b     = (const float*)d_in[23];
    const float* latent_w  = (const float*)d_in[24];

    char* base = (char*)d_ws;
    size_t off = 0;
    auto alloc = [&](size_t bytes) { void* p = base + off; off += (bytes + 255) & ~255ULL; return p; };

    float* embeds  = (float*)alloc((size_t)B_ * T_ * D_ * 4);
    float* hbuf    = (float*)alloc((size_t)B_ * T_ * D_ * 4);
    float* hidbuf  = (float*)alloc((size_t)B_ * T_ * D_ * 4);
    float* partm   = (float*)alloc((size_t)NCH * NTOK * 4);
    float* parts_  = (float*)alloc((size_t)NCH * NTOK * 4);
    float* llogit  = (float*)alloc((size_t)NTOK * 4);
    float* nllbuf  = (float*)alloc((size_t)NTOK * 4);
    unsigned short* wqkvT  = (unsigned short*)alloc((size_t)3072 * 1024 * 2);
    unsigned short* woT    = (unsigned short*)alloc((size_t)1024 * 1024 * 2);
    unsigned short* W1T    = (unsigned short*)alloc((size_t)4096 * 1024 * 2);
    unsigned short* W2T    = (unsigned short*)alloc((size_t)1024 * 4096 * 2);
    unsigned short* embedbf = (unsigned short*)alloc((size_t)V_ * D_ * 2);
    unsigned short* hidbf  = (unsigned short*)alloc((size_t)B_ * T_ * D_ * 2);
    unsigned short* abf    = (unsigned short*)alloc((size_t)1024 * D_ * 2);
    unsigned short* ctxbf  = (unsigned short*)alloc((size_t)1024 * D_ * 2);
    unsigned short* ffbw   = (unsigned short*)alloc((size_t)1024 * DFF_ * 2);
    unsigned short* qbf    = (unsigned short*)alloc((size_t)1024 * D_ * 2);
    unsigned short* kcbf   = (unsigned short*)alloc((size_t)B_ * T_ * D_ * 2);
    unsigned short* vcbf   = (unsigned short*)alloc((size_t)B_ * T_ * D_ * 2);
    unsigned short* vtc    = (unsigned short*)alloc((size_t)B_ * H_ * DH_ * T_ * 2);

    // weight prep (transpose + LoRA merge + bf16)
    k_prep_w<<<dim3(3072 / 64, 1024 / 64), 256, 0, stream>>>(Wqkv, Aq, Bq, wqkvT, 1024, 3072, 1);
    k_prep_w<<<dim3(1024 / 64, 1024 / 64), 256, 0, stream>>>(Wo, Ao, Bo, woT, 1024, 1024, 1);
    k_prep_w<<<dim3(4096 / 64, 1024 / 64), 256, 0, stream>>>(W1, nullptr, nullptr, W1T, 1024, 4096, 0);
    k_prep_w<<<dim3(1024 / 64, 4096 / 64), 256, 0, stream>>>(W2, nullptr, nullptr, W2T, 4096, 1024, 0);
    k_f2bf<<<(V_ * D_ / 4 + 255) / 256, 256, 0, stream>>>(embed, embedbf, V_ * D_ / 4);
    k_embed_gather<<<B_ * T_, 256, 0, stream>>>(input_ids, embed, embeds);

    auto run_pass = [&](int c0, int c1) {
        int range = c1 - c0;
        int Mr = B_ * range;
        int gy = (Mr + 127) / 128;
        int qt = (range + 63) / 64;
        // ln1 (fused h = embeds + Wpos -> hbuf)
        k_ln<<<Mr, 256, 0, stream>>>(nullptr, embeds, Wpos, ln1_s, ln1_b, hbuf, nullptr, abf, c0, range, 0);
        k_mgemm<1><<<dim3(3072 / 128, gy), 256, 0, stream>>>(abf, wqkvT, bqkv, nullptr, qbf, kcbf, vcbf,
                                                             Mr, 3072, 1024, c0, range, 1);
        k_vtrans<<<dim3(qt, H_, B_), 256, 0, stream>>>(vcbf, vtc, c0, range);
        k_fattn<<<dim3(qt, H_, B_), 256, 0, stream>>>(qbf, kcbf, vtc, ctxbf, c0, range);
        k_mgemm<2><<<dim3(1024 / 128, gy, 2), 256, 0, stream>>>(ctxbf, woT, bo, hbuf, nullptr, nullptr, nullptr,
                                                                Mr, 1024, 1024, c0, range, 2);
        k_ln<<<Mr, 256, 0, stream>>>(hbuf, nullptr, nullptr, ln2_s, ln2_b, nullptr, nullptr, abf, c0, range, 0);
        k_mgemm<3><<<dim3(4096 / 128, gy), 256, 0, stream>>>(abf, W1T, b1, nullptr, ffbw, nullptr, nullptr,
                                                             Mr, 4096, 1024, c0, range, 1);
        k_mgemm<2><<<dim3(1024 / 128, gy, 4), 256, 0, stream>>>(ffbw, W2T, b2, hbuf, nullptr, nullptr, nullptr,
                                                                Mr, 1024, 4096, c0, range, 4);
        k_ln<<<Mr, 256, 0, stream>>>(hbuf, nullptr, nullptr, lnf_s, lnf_b, nullptr, hidbuf, hidbf, c0, range, 1);
    };

    run_pass(0, 512);
    k_latent0<<<(B_ * D_ + 255) / 256, 256, 0, stream>>>(hidbuf, latent_w, embeds);
    run_pass(512, 513);
    k_latent1<<<(B_ * D_ + 255) / 256, 256, 0, stream>>>(hidbuf, embeds, 513);
    run_pass(513, 514);
    k_latent1<<<(B_ * D_ + 255) / 256, 256, 0, stream>>>(hidbuf, embeds, 514);
    run_pass(514, 515);
    k_latent1<<<(B_ * D_ + 255) / 256, 256, 0, stream>>>(hidbuf, embeds, 515);
    run_pass(515, 1024);

    // loss
    k_loss1m<<<dim3(NCH, (NTOK + 255) / 256), 256, 0, stream>>>(hidbf, embedbf, labels, partm, parts_, llogit);
    k_loss2a<<<(NTOK + 255) / 256, 256, 0, stream>>>(partm, parts_, llogit, nllbuf);
    k_loss2b<<<1, 256, 0, stream>>>(nllbuf, (float*)d_out);
}

// Round 5
// 1553.993 us; speedup vs baseline: 4.5689x; 1.0030x over previous
//
#include <hip/hip_runtime.h>
#include <math.h>

#define B_   2
#define T_   1024
#define D_   1024
#define H_   16
#define DH_  64
#define DFF_ 4096
#define V_   32000
#define NTOK 2046      // B*(T-1)
#define NCH  250       // V_/128 vocab chunks for loss partials

typedef __attribute__((ext_vector_type(8))) short short8;
typedef __attribute__((ext_vector_type(4))) float floatx4;

__device__ __forceinline__ unsigned short f2bf(float x) {
    unsigned int u = __float_as_uint(x);
    unsigned int r = (u + 0x7fffu + ((u >> 16) & 1u)) >> 16;
    return (unsigned short)r;
}

__device__ __forceinline__ void gld_lds16(void* lds, const void* g) {
    __builtin_amdgcn_global_load_lds(
        (const __attribute__((address_space(1))) void*)g,
        (__attribute__((address_space(3))) void*)lds, 16, 0, 0);
}

__device__ __forceinline__ float gelu_tanh(float x) {
    float x3 = x * x * x;
    return 0.5f * x * (1.0f + tanhf(0.7978845608028654f * (x + 0.044715f * x3)));
}

// ---------------- weight prep: out[n*K+k] = bf16(W[k*N+n] + 2*(A@Bm)[k,n]) ----------------
__global__ __launch_bounds__(256) void k_prep_w(const float* __restrict__ W,
        const float* __restrict__ A, const float* __restrict__ Bm,
        unsigned short* __restrict__ out, int K, int N, int lora) {
    __shared__ float t[64][65];
    int n0 = blockIdx.x * 64, k0 = blockIdx.y * 64;
    int tid = threadIdx.x;
    int nn = tid & 63, kb = tid >> 6;
    for (int i = 0; i < 16; i++) {
        int kk = kb * 16 + i;
        float v = W[(size_t)(k0 + kk) * N + n0 + nn];
        if (lora) {
            float s = 0.f;
#pragma unroll
            for (int r = 0; r < 8; r++) s += A[(k0 + kk) * 8 + r] * Bm[r * N + n0 + nn];
            v += 2.0f * s;
        }
        t[kk][nn] = v;
    }
    __syncthreads();
    int kk2 = tid & 63, nb = tid >> 6;
    for (int j = 0; j < 16; j++) {
        int nn2 = nb * 16 + j;
        out[(size_t)(n0 + nn2) * K + k0 + kk2] = f2bf(t[kk2][nn2]);
    }
}

// ---------------- fp32 -> bf16 bulk convert ----------------
__global__ void k_f2bf(const float* __restrict__ in, unsigned short* __restrict__ out, int n4) {
    int i = blockIdx.x * 256 + threadIdx.x;
    if (i >= n4) return;
    float4 v = ((const float4*)in)[i];
    ushort4 o;
    o.x = f2bf(v.x); o.y = f2bf(v.y); o.z = f2bf(v.z); o.w = f2bf(v.w);
    ((ushort4*)out)[i] = o;
}

// ---------------- embedding gather ----------------
__global__ void k_embed_gather(const int* __restrict__ ids, const float* __restrict__ embed,
                               float* __restrict__ embeds) {
    int bt = blockIdx.x;
    int d4 = threadIdx.x;
    int id = ids[bt];
    ((float4*)embeds)[(size_t)bt * 256 + d4] = ((const float4*)embed)[(size_t)id * 256 + d4];
}

// ---------------- LayerNorm. If embeds!=null: x = embeds+Wpos (writes hout); else x = in. ----------------
__global__ __launch_bounds__(256) void k_ln(const float* __restrict__ in,
                                            const float* __restrict__ embeds, const float* __restrict__ Wpos,
                                            const float* __restrict__ sc, const float* __restrict__ bi,
                                            float* __restrict__ hout, float* __restrict__ outf,
                                            unsigned short* __restrict__ outbf,
                                            int c0, int range, int strided_bf) {
    int r = blockIdx.x;
    int b = r / range, pos = c0 + r % range;
    size_t rowoff = (size_t)(b * T_ + pos) * D_;
    int tid = threadIdx.x;
    float xv[4];
    if (embeds) {
#pragma unroll
        for (int j = 0; j < 4; j++) {
            int i = tid + j * 256;
            xv[j] = embeds[rowoff + i] + Wpos[(size_t)pos * D_ + i];
            hout[rowoff + i] = xv[j];
        }
    } else {
#pragma unroll
        for (int j = 0; j < 4; j++) xv[j] = in[rowoff + tid + j * 256];
    }
    float s1 = 0.f, s2 = 0.f;
#pragma unroll
    for (int j = 0; j < 4; j++) { s1 += xv[j]; s2 += xv[j] * xv[j]; }
    __shared__ float r1[256], r2[256];
    r1[tid] = s1; r2[tid] = s2; __syncthreads();
    for (int o = 128; o > 0; o >>= 1) {
        if (tid < o) { r1[tid] += r1[tid + o]; r2[tid] += r2[tid + o]; }
        __syncthreads();
    }
    float mean = r1[0] * (1.0f / D_);
    float var = r2[0] * (1.0f / D_) - mean * mean;
    float inv = rsqrtf(var + 1e-5f);
    size_t bfrow = strided_bf ? (size_t)(b * T_ + pos) : (size_t)r;
#pragma unroll
    for (int j = 0; j < 4; j++) {
        int i = tid + j * 256;
        float y = (xv[j] - mean) * inv * sc[i] + bi[i];
        if (outf) outf[rowoff + i] = y;
        outbf[bfrow * D_ + i] = f2bf(y);
    }
}

// ---------------- MFMA GEMM: C[M,N] = A[M,K](bf16) @ Bt[N,K]^T(bf16) ----------------
// MODE 1: qkv scatter -> bf16 q / k cache / v cache (u2=vcbf)
// MODE 4: qkv scatter -> bf16 q / k cache / v DIRECT into transposed vtc (u2=vtc)
// MODE 2: split-K atomic residual add fp32 (grid.z = K segments)
// MODE 3: gelu -> bf16
template <int MODE>
__global__ __launch_bounds__(256) void k_mgemm(const unsigned short* __restrict__ Abf,
        const unsigned short* __restrict__ Bt, const float* __restrict__ bias,
        float* __restrict__ o0, unsigned short* __restrict__ u0,
        unsigned short* __restrict__ u1, unsigned short* __restrict__ u2,
        int M, int N, int K, int c0, int range, int ksegs) {
    __shared__ short8 As_v[512];
    __shared__ short8 Bs_v[512];
    int tid = threadIdx.x;
    int lane = tid & 63, w = tid >> 6;
    int quad = lane >> 4, l15 = lane & 15;
    int row0 = blockIdx.y * 128, col0 = blockIdx.x * 128;
    int kseg = blockIdx.z;
    int Klen = K / ksegs;
    int ksoff = kseg * Klen;
    int rh = (w >> 1) * 64, ch = (w & 1) * 64;

    int cA0 = w * 128 + lane, cA1 = cA0 + 64;
    int rA0 = cA0 & 127, kgA0 = cA0 >> 7;
    int rA1 = cA1 & 127, kgA1 = cA1 >> 7;
    int rowA0 = row0 + rA0; if (rowA0 >= M) rowA0 = M - 1;
    int rowA1 = row0 + rA1; if (rowA1 >= M) rowA1 = M - 1;
    const unsigned short* ga0 = Abf + (size_t)rowA0 * K + ksoff + kgA0 * 8;
    const unsigned short* ga1 = Abf + (size_t)rowA1 * K + ksoff + kgA1 * 8;
    const unsigned short* gb0 = Bt + (size_t)(col0 + rA0) * K + ksoff + kgA0 * 8;
    const unsigned short* gb1 = Bt + (size_t)(col0 + rA1) * K + ksoff + kgA1 * 8;

    floatx4 acc[4][4];
#pragma unroll
    for (int i = 0; i < 4; i++)
#pragma unroll
        for (int j = 0; j < 4; j++)
#pragma unroll
            for (int k = 0; k < 4; k++) acc[i][j][k] = 0.f;

    int iters = Klen >> 5;
    for (int it = 0; it < iters; ++it) {
        __syncthreads();
        gld_lds16(&As_v[w * 128],      ga0);
        gld_lds16(&As_v[w * 128 + 64], ga1);
        gld_lds16(&Bs_v[w * 128],      gb0);
        gld_lds16(&Bs_v[w * 128 + 64], gb1);
        ga0 += 32; ga1 += 32; gb0 += 32; gb1 += 32;
        __syncthreads();
        short8 af[4], bfv[4];
#pragma unroll
        for (int mi = 0; mi < 4; mi++) af[mi] = As_v[quad * 128 + rh + mi * 16 + l15];
#pragma unroll
        for (int nj = 0; nj < 4; nj++) bfv[nj] = Bs_v[quad * 128 + ch + nj * 16 + l15];
#pragma unroll
        for (int mi = 0; mi < 4; mi++)
#pragma unroll
            for (int nj = 0; nj < 4; nj++)
                acc[mi][nj] = __builtin_amdgcn_mfma_f32_16x16x32_bf16(af[mi], bfv[nj], acc[mi][nj], 0, 0, 0);
    }

#pragma unroll
    for (int mi = 0; mi < 4; mi++)
#pragma unroll
        for (int reg = 0; reg < 4; reg++) {
            int r = row0 + rh + mi * 16 + quad * 4 + reg;
            if (r >= M) continue;
            int b = r / range, pos = c0 + r % range;
#pragma unroll
            for (int nj = 0; nj < 4; nj++) {
                int n = col0 + ch + nj * 16 + l15;
                if constexpr (MODE == 1 || MODE == 4) {
                    float v = acc[mi][nj][reg] + bias[n];
                    if (n < 1024) u0[(size_t)r * 1024 + n] = f2bf(v);
                    else if (n < 2048) u1[(size_t)(b * T_ + pos) * 1024 + (n - 1024)] = f2bf(v);
                    else {
                        if constexpr (MODE == 1) {
                            u2[(size_t)(b * T_ + pos) * 1024 + (n - 2048)] = f2bf(v);
                        } else {
                            int idx = n - 2048, h = idx >> 6, d = idx & 63;
                            u2[(size_t)((b * 16 + h) * 64 + d) * T_ + pos] = f2bf(v);
                        }
                    }
                } else if constexpr (MODE == 2) {
                    float v = acc[mi][nj][reg] + (kseg == 0 ? bias[n] : 0.f);
                    atomicAdd(&o0[(size_t)(b * T_ + pos) * D_ + n], v);
                } else if constexpr (MODE == 3) {
                    float v = acc[mi][nj][reg] + bias[n];
                    u0[(size_t)r * N + n] = f2bf(gelu_tanh(v));
                }
            }
        }
}

// ---------------- V transpose into global vtc[(b*16+h)*64+d][T] (big passes) ----------------
__global__ __launch_bounds__(256) void k_vtrans(const unsigned short* __restrict__ vcbf,
        unsigned short* __restrict__ vtc, int c0, int range) {
    __shared__ unsigned short ts[64][72];
    int pt = blockIdx.x, h = blockIdx.y, b = blockIdx.z;
    int t = threadIdx.x;
#pragma unroll
    for (int i = 0; i < 2; i++) {
        int idx = t + i * 256;
        int p = idx >> 3, c8 = idx & 7;
        int pos = c0 + pt * 64 + p;
        if (pos < c0 + range) {
            short8 v = *(const short8*)&vcbf[(size_t)(b * T_ + pos) * D_ + h * 64 + c8 * 8];
            *(short8*)&ts[p][c8 * 8] = v;
        }
    }
    __syncthreads();
#pragma unroll
    for (int i = 0; i < 2; i++) {
        int idx = t + i * 256;
        int d = idx >> 3, p8 = idx & 7;
        unsigned short tmp[8];
#pragma unroll
        for (int j = 0; j < 8; j++) tmp[j] = ts[p8 * 8 + j][d];
        int pos0 = c0 + pt * 64 + p8 * 8;
        size_t rb = (size_t)((b * 16 + h) * 64 + d) * T_;
        if (pos0 + 7 < c0 + range) {
            *(short8*)&vtc[rb + pos0] = *(short8*)tmp;
        } else {
            for (int j = 0; j < 8; j++)
                if (pos0 + j < c0 + range) vtc[rb + pos0 + j] = tmp[j];
        }
    }
}

// ---------------- barrier-free MFMA flash attention ----------------
__global__ __launch_bounds__(256) void k_fattn(const unsigned short* __restrict__ qbf,
        const unsigned short* __restrict__ kcbf, const unsigned short* __restrict__ vtc,
        unsigned short* __restrict__ ctxbf, int c0, int range) {
    __shared__ unsigned short pw[4][16][72];
    int tid = threadIdx.x;
    int w = tid >> 6, lane = tid & 63, quad = lane >> 4, l15 = lane & 15;
    int qt = blockIdx.x, h = blockIdx.y, b = blockIdx.z;
    int q0 = qt * 64 + w * 16;
    if (q0 >= range) return;                 // no barriers in this kernel -> safe
    int qtop = q0 + 15; if (qtop >= range) qtop = range - 1;
    int nkt = (c0 + qtop) / 64 + 1;

    int qrow = q0 + l15; if (qrow >= range) qrow = range - 1;
    const unsigned short* qp = qbf + (size_t)(b * range + qrow) * D_ + h * 64 + quad * 8;
    short8 aq0 = *(const short8*)qp;
    short8 aq1 = *(const short8*)(qp + 32);

    floatx4 oacc[4];
#pragma unroll
    for (int dg = 0; dg < 4; dg++)
#pragma unroll
        for (int r = 0; r < 4; r++) oacc[dg][r] = 0.f;
    float m_r[4] = {-1e30f, -1e30f, -1e30f, -1e30f};
    float l_r[4] = {0.f, 0.f, 0.f, 0.f};

    const unsigned short* kb_p = kcbf + (size_t)b * T_ * D_ + h * 64 + quad * 8;
    const unsigned short* vb_p = vtc + (size_t)((b * 16 + h) * 64 + l15) * T_ + quad * 8;

    for (int kt = 0; kt < nkt; kt++) {
        int kb = kt * 64;
        floatx4 s[4];
#pragma unroll
        for (int g = 0; g < 4; g++) {
            const unsigned short* kp = kb_p + (size_t)(kb + g * 16 + l15) * D_;
            short8 bk0 = *(const short8*)kp;
            short8 bk1 = *(const short8*)(kp + 32);
            floatx4 z; z[0] = 0.f; z[1] = 0.f; z[2] = 0.f; z[3] = 0.f;
            z = __builtin_amdgcn_mfma_f32_16x16x32_bf16(aq0, bk0, z, 0, 0, 0);
            s[g] = __builtin_amdgcn_mfma_f32_16x16x32_bf16(aq1, bk1, z, 0, 0, 0);
        }
#pragma unroll
        for (int r = 0; r < 4; r++) {
            int qpos = c0 + q0 + quad * 4 + r;
            float mx = -1e30f;
#pragma unroll
            for (int g = 0; g < 4; g++) {
                int kpos = kb + g * 16 + l15;
                float sv = (kpos <= qpos) ? s[g][r] * 0.125f : -1e30f;
                s[g][r] = sv; mx = fmaxf(mx, sv);
            }
            mx = fmaxf(mx, __shfl_xor(mx, 1));
            mx = fmaxf(mx, __shfl_xor(mx, 2));
            mx = fmaxf(mx, __shfl_xor(mx, 4));
            mx = fmaxf(mx, __shfl_xor(mx, 8));
            float mn = fmaxf(m_r[r], mx);
            float alpha = __expf(m_r[r] - mn);
            m_r[r] = mn;
            float ls = 0.f;
#pragma unroll
            for (int g = 0; g < 4; g++) {
                float p = __expf(s[g][r] - mn);
                s[g][r] = p; ls += p;
            }
            ls += __shfl_xor(ls, 1);
            ls += __shfl_xor(ls, 2);
            ls += __shfl_xor(ls, 4);
            ls += __shfl_xor(ls, 8);
            l_r[r] = l_r[r] * alpha + ls;
#pragma unroll
            for (int dg = 0; dg < 4; dg++) oacc[dg][r] *= alpha;
        }
#pragma unroll
        for (int g = 0; g < 4; g++)
#pragma unroll
            for (int r = 0; r < 4; r++)
                pw[w][quad * 4 + r][g * 16 + l15] = f2bf(s[g][r]);
        short8 ap0 = *(const short8*)&pw[w][l15][quad * 8];
        short8 ap1 = *(const short8*)&pw[w][l15][32 + quad * 8];
#pragma unroll
        for (int dg = 0; dg < 4; dg++) {
            const unsigned short* vp = vb_p + (size_t)(dg * 16) * T_ + kb;
            short8 bv0 = *(const short8*)vp;
            short8 bv1 = *(const short8*)(vp + 32);
            oacc[dg] = __builtin_amdgcn_mfma_f32_16x16x32_bf16(ap0, bv0, oacc[dg], 0, 0, 0);
            oacc[dg] = __builtin_amdgcn_mfma_f32_16x16x32_bf16(ap1, bv1, oacc[dg], 0, 0, 0);
        }
    }
#pragma unroll
    for (int dg = 0; dg < 4; dg++)
#pragma unroll
        for (int r = 0; r < 4; r++) {
            int qloc = q0 + quad * 4 + r;
            if (qloc < range)
                ctxbf[(size_t)(b * range + qloc) * D_ + h * 64 + dg * 16 + l15] =
                    f2bf(oacc[dg][r] / l_r[r]);
        }
}

// ---------------- latent vec fills ----------------
__global__ void k_latent0(const float* __restrict__ hid, const float* __restrict__ lw,
                          float* __restrict__ embeds) {
    int idx = blockIdx.x * 256 + threadIdx.x;
    if (idx >= B_ * D_) return;
    int b = idx / D_, d = idx % D_;
    float w0 = lw[0], w1 = lw[1], w2 = lw[2];
    float mx = fmaxf(w0, fmaxf(w1, w2));
    float e0 = __expf(w0 - mx), e1 = __expf(w1 - mx), e2 = __expf(w2 - mx);
    float inv = 1.0f / (e0 + e1 + e2);
    float v = (e0 * hid[(size_t)(b * T_ + 509) * D_ + d] +
               e1 * hid[(size_t)(b * T_ + 510) * D_ + d] +
               e2 * hid[(size_t)(b * T_ + 511) * D_ + d]) * inv;
    embeds[(size_t)(b * T_ + 512) * D_ + d] = v;
}

__global__ void k_latent1(const float* __restrict__ hid, float* __restrict__ embeds, int tok) {
    int idx = blockIdx.x * 256 + threadIdx.x;
    if (idx >= B_ * D_) return;
    int b = idx / D_, d = idx % D_;
    embeds[(size_t)(b * T_ + tok) * D_ + d] = hid[(size_t)(b * T_ + tok - 1) * D_ + d];
}

// ---------------- loss MFMA GEMM: 128x128 tile, L2-friendly grid (x=rowtile, y=chunk) ----------------
__global__ __launch_bounds__(256) void k_loss1m(const unsigned short* __restrict__ hidbf,
        const unsigned short* __restrict__ embedbf, const int* __restrict__ labels,
        float* __restrict__ partm, float* __restrict__ parts, float* __restrict__ llogit) {
    __shared__ short8 As_v[512];
    __shared__ short8 Bs_v[512];
    __shared__ int lds_lab[128];
    __shared__ float lds_pm[128][2];
    __shared__ float lds_ps[128][2];
    int tid = threadIdx.x;
    int lane = tid & 63, w = tid >> 6;
    int quad = lane >> 4, l15 = lane & 15;
    int chunk = blockIdx.y;                     // <- swapped: y = vocab chunk
    int row0 = blockIdx.x * 128, v0 = chunk * 128;
    int rh = (w >> 1) * 64, ch = (w & 1) * 64;

    if (tid < 128) {
        int tok = row0 + tid;
        lds_lab[tid] = (tok < NTOK) ? labels[tok + 1 + (tok >= 1023)] : -1;
    }

    int cA0 = w * 128 + lane, cA1 = cA0 + 64;
    int rA0 = cA0 & 127, kgA0 = cA0 >> 7;
    int rA1 = cA1 & 127, kgA1 = cA1 >> 7;
    int tokA0 = row0 + rA0; if (tokA0 >= NTOK) tokA0 = NTOK - 1;
    int tokA1 = row0 + rA1; if (tokA1 >= NTOK) tokA1 = NTOK - 1;
    const unsigned short* ga0 = hidbf + (size_t)(tokA0 + (tokA0 >= 1023)) * D_ + kgA0 * 8;
    const unsigned short* ga1 = hidbf + (size_t)(tokA1 + (tokA1 >= 1023)) * D_ + kgA1 * 8;
    const unsigned short* gb0 = embedbf + (size_t)(v0 + rA0) * D_ + kgA0 * 8;
    const unsigned short* gb1 = embedbf + (size_t)(v0 + rA1) * D_ + kgA1 * 8;

    floatx4 acc[4][4];
#pragma unroll
    for (int i = 0; i < 4; i++)
#pragma unroll
        for (int j = 0; j < 4; j++)
#pragma unroll
            for (int k = 0; k < 4; k++) acc[i][j][k] = 0.f;

    for (int it = 0; it < D_ / 32; ++it) {
        __syncthreads();
        gld_lds16(&As_v[w * 128],      ga0);
        gld_lds16(&As_v[w * 128 + 64], ga1);
        gld_lds16(&Bs_v[w * 128],      gb0);
        gld_lds16(&Bs_v[w * 128 + 64], gb1);
        ga0 += 32; ga1 += 32; gb0 += 32; gb1 += 32;
        __syncthreads();
        short8 af[4], bfv[4];
#pragma unroll
        for (int mi = 0; mi < 4; mi++) af[mi] = As_v[quad * 128 + rh + mi * 16 + l15];
#pragma unroll
        for (int nj = 0; nj < 4; nj++) bfv[nj] = Bs_v[quad * 128 + ch + nj * 16 + l15];
#pragma unroll
        for (int mi = 0; mi < 4; mi++)
#pragma unroll
            for (int nj = 0; nj < 4; nj++)
                acc[mi][nj] = __builtin_amdgcn_mfma_f32_16x16x32_bf16(af[mi], bfv[nj], acc[mi][nj], 0, 0, 0);
    }

#pragma unroll
    for (int mi = 0; mi < 4; mi++)
#pragma unroll
        for (int reg = 0; reg < 4; reg++) {
            int rloc = rh + mi * 16 + quad * 4 + reg;
            int lab = lds_lab[rloc];
            float vm = -1e30f;
#pragma unroll
            for (int nj = 0; nj < 4; nj++) {
                float v = acc[mi][nj][reg];
                int vcol = v0 + ch + nj * 16 + l15;
                if (vcol == lab) llogit[row0 + rloc] = v;
                vm = fmaxf(vm, v);
            }
            for (int off = 1; off < 16; off <<= 1) vm = fmaxf(vm, __shfl_xor(vm, off));
            float ss = 0.f;
#pragma unroll
            for (int nj = 0; nj < 4; nj++) ss += __expf(acc[mi][nj][reg] - vm);
            for (int off = 1; off < 16; off <<= 1) ss += __shfl_xor(ss, off);
            if (l15 == 0) { lds_pm[rloc][ch >> 6] = vm; lds_ps[rloc][ch >> 6] = ss; }
        }
    __syncthreads();
    if (tid < 128) {
        int tok = row0 + tid;
        if (tok < NTOK) {
            float m0 = lds_pm[tid][0], m1 = lds_pm[tid][1];
            float M = fmaxf(m0, m1);
            float S = lds_ps[tid][0] * __expf(m0 - M) + lds_ps[tid][1] * __expf(m1 - M);
            partm[(size_t)chunk * NTOK + tok] = M;
            parts[(size_t)chunk * NTOK + tok] = S;
        }
    }
}

// ---------------- loss combine ----------------
__global__ void k_loss2a(const float* __restrict__ partm, const float* __restrict__ parts,
                         const float* __restrict__ ll, float* __restrict__ nll) {
    int tok = blockIdx.x * 256 + threadIdx.x;
    if (tok >= NTOK) return;
    float M = -1e30f;
    for (int c = 0; c < NCH; c++) M = fmaxf(M, partm[(size_t)c * NTOK + tok]);
    float S = 0.f;
    for (int c = 0; c < NCH; c++)
        S += parts[(size_t)c * NTOK + tok] * __expf(partm[(size_t)c * NTOK + tok] - M);
    nll[tok] = logf(S) + M - ll[tok];
}

__global__ __launch_bounds__(256) void k_loss2b(const float* __restrict__ nll, float* __restrict__ out) {
    __shared__ float red[256];
    int tid = threadIdx.x;
    float s = 0.f;
    for (int i = tid; i < NTOK; i += 256) s += nll[i];
    red[tid] = s; __syncthreads();
    for (int o = 128; o > 0; o >>= 1) {
        if (tid < o) red[tid] += red[tid + o];
        __syncthreads();
    }
    if (tid == 0) out[0] = red[0] / (float)NTOK;
}

// ---------------- host ----------------
extern "C" void kernel_launch(void* const* d_in, const int* in_sizes, int n_in,
                              void* d_out, int out_size, void* d_ws, size_t ws_size,
                              hipStream_t stream) {
    const int*   input_ids = (const int*)d_in[0];
    const int*   labels    = (const int*)d_in[2];
    const float* embed     = (const float*)d_in[4];
    const float* Wpos      = (const float*)d_in[5];
    const float* Wqkv      = (const float*)d_in[6];
    const float* bqkv      = (const float*)d_in[7];
    const float* Aq        = (const float*)d_in[8];
    const float* Bq        = (const float*)d_in[9];
    const float* Wo        = (const float*)d_in[10];
    const float* bo        = (const float*)d_in[11];
    const float* Ao        = (const float*)d_in[12];
    const float* Bo        = (const float*)d_in[13];
    const float* W1        = (const float*)d_in[14];
    const float* b1        = (const float*)d_in[15];
    const float* W2        = (const float*)d_in[16];
    const float* b2        = (const float*)d_in[17];
    const float* ln1_s     = (const float*)d_in[18];
    const float* ln1_b     = (const float*)d_in[19];
    const float* ln2_s     = (const float*)d_in[20];
    const float* ln2_b     = (const float*)d_in[21];
    const float* lnf_s     = (const float*)d_in[22];
    const float* lnf_b     = (const float*)d_in[23];
    const float* latent_w  = (const float*)d_in[24];

    char* base = (char*)d_ws;
    size_t off = 0;
    auto alloc = [&](size_t bytes) { void* p = base + off; off += (bytes + 255) & ~255ULL; return p; };

    float* embeds  = (float*)alloc((size_t)B_ * T_ * D_ * 4);
    float* hbuf    = (float*)alloc((size_t)B_ * T_ * D_ * 4);
    float* hidbuf  = (float*)alloc((size_t)B_ * T_ * D_ * 4);
    float* partm   = (float*)alloc((size_t)NCH * NTOK * 4);
    float* parts_  = (float*)alloc((size_t)NCH * NTOK * 4);
    float* llogit  = (float*)alloc((size_t)NTOK * 4);
    float* nllbuf  = (float*)alloc((size_t)NTOK * 4);
    unsigned short* wqkvT  = (unsigned short*)alloc((size_t)3072 * 1024 * 2);
    unsigned short* woT    = (unsigned short*)alloc((size_t)1024 * 1024 * 2);
    unsigned short* W1T    = (unsigned short*)alloc((size_t)4096 * 1024 * 2);
    unsigned short* W2T    = (unsigned short*)alloc((size_t)1024 * 4096 * 2);
    unsigned short* embedbf = (unsigned short*)alloc((size_t)V_ * D_ * 2);
    unsigned short* hidbf  = (unsigned short*)alloc((size_t)B_ * T_ * D_ * 2);
    unsigned short* abf    = (unsigned short*)alloc((size_t)1024 * D_ * 2);
    unsigned short* ctxbf  = (unsigned short*)alloc((size_t)1024 * D_ * 2);
    unsigned short* ffbw   = (unsigned short*)alloc((size_t)1024 * DFF_ * 2);
    unsigned short* qbf    = (unsigned short*)alloc((size_t)1024 * D_ * 2);
    unsigned short* kcbf   = (unsigned short*)alloc((size_t)B_ * T_ * D_ * 2);
    unsigned short* vcbf   = (unsigned short*)alloc((size_t)B_ * T_ * D_ * 2);
    unsigned short* vtc    = (unsigned short*)alloc((size_t)B_ * H_ * DH_ * T_ * 2);

    // weight prep (transpose + LoRA merge + bf16)
    k_prep_w<<<dim3(3072 / 64, 1024 / 64), 256, 0, stream>>>(Wqkv, Aq, Bq, wqkvT, 1024, 3072, 1);
    k_prep_w<<<dim3(1024 / 64, 1024 / 64), 256, 0, stream>>>(Wo, Ao, Bo, woT, 1024, 1024, 1);
    k_prep_w<<<dim3(4096 / 64, 1024 / 64), 256, 0, stream>>>(W1, nullptr, nullptr, W1T, 1024, 4096, 0);
    k_prep_w<<<dim3(1024 / 64, 4096 / 64), 256, 0, stream>>>(W2, nullptr, nullptr, W2T, 4096, 1024, 0);
    k_f2bf<<<(V_ * D_ / 4 + 255) / 256, 256, 0, stream>>>(embed, embedbf, V_ * D_ / 4);
    k_embed_gather<<<B_ * T_, 256, 0, stream>>>(input_ids, embed, embeds);

    auto run_pass = [&](int c0, int c1) {
        int range = c1 - c0;
        int Mr = B_ * range;
        int gy = (Mr + 127) / 128;
        int qt = (range + 63) / 64;
        // ln1 (fused h = embeds + Wpos -> hbuf)
        k_ln<<<Mr, 256, 0, stream>>>(nullptr, embeds, Wpos, ln1_s, ln1_b, hbuf, nullptr, abf, c0, range, 0);
        if (range == 1) {
            // qkv with v scattered directly into transposed vtc (skip k_vtrans)
            k_mgemm<4><<<dim3(3072 / 128, gy), 256, 0, stream>>>(abf, wqkvT, bqkv, nullptr, qbf, kcbf, vtc,
                                                                 Mr, 3072, 1024, c0, range, 1);
        } else {
            k_mgemm<1><<<dim3(3072 / 128, gy), 256, 0, stream>>>(abf, wqkvT, bqkv, nullptr, qbf, kcbf, vcbf,
                                                                 Mr, 3072, 1024, c0, range, 1);
            k_vtrans<<<dim3(qt, H_, B_), 256, 0, stream>>>(vcbf, vtc, c0, range);
        }
        k_fattn<<<dim3(qt, H_, B_), 256, 0, stream>>>(qbf, kcbf, vtc, ctxbf, c0, range);
        k_mgemm<2><<<dim3(1024 / 128, gy, 2), 256, 0, stream>>>(ctxbf, woT, bo, hbuf, nullptr, nullptr, nullptr,
                                                                Mr, 1024, 1024, c0, range, 2);
        k_ln<<<Mr, 256, 0, stream>>>(hbuf, nullptr, nullptr, ln2_s, ln2_b, nullptr, nullptr, abf, c0, range, 0);
        k_mgemm<3><<<dim3(4096 / 128, gy), 256, 0, stream>>>(abf, W1T, b1, nullptr, ffbw, nullptr, nullptr,
                                                             Mr, 4096, 1024, c0, range, 1);
        k_mgemm<2><<<dim3(1024 / 128, gy, 4), 256, 0, stream>>>(ffbw, W2T, b2, hbuf, nullptr, nullptr, nullptr,
                                                                Mr, 1024, 4096, c0, range, 4);
        k_ln<<<Mr, 256, 0, stream>>>(hbuf, nullptr, nullptr, lnf_s, lnf_b, nullptr, hidbuf, hidbf, c0, range, 1);
    };

    run_pass(0, 512);
    k_latent0<<<(B_ * D_ + 255) / 256, 256, 0, stream>>>(hidbuf, latent_w, embeds);
    run_pass(512, 513);
    k_latent1<<<(B_ * D_ + 255) / 256, 256, 0, stream>>>(hidbuf, embeds, 513);
    run_pass(513, 514);
    k_latent1<<<(B_ * D_ + 255) / 256, 256, 0, stream>>>(hidbuf, embeds, 514);
    run_pass(514, 515);
    k_latent1<<<(B_ * D_ + 255) / 256, 256, 0, stream>>>(hidbuf, embeds, 515);
    run_pass(515, 1024);

    // loss: grid x = row tiles (16), y = vocab chunks (250) for L2 reuse of embed slices
    k_loss1m<<<dim3((NTOK + 127) / 128, NCH), 256, 0, stream>>>(hidbf, embedbf, labels, partm, parts_, llogit);
    k_loss2a<<<(NTOK + 255) / 256, 256, 0, stream>>>(partm, parts_, llogit, nllbuf);
    k_loss2b<<<1, 256, 0, stream>>>(nllbuf, (float*)d_out);
}